// Round 1
// baseline (567.385 us; speedup 1.0000x reference)
//
#include <hip/hip_runtime.h>
#include <cstddef>

#define BB 64
#define TT 400
#define EE 128
#define HH 512
#define H4 1024
#define VV 50000

// ---- d_out layout (floats), reference return order ----
#define OFF_OUT     0
#define OFF_CURHID  (BB*VV)                    // 3,200,000
#define OFF_ATTN    (OFF_CURHID + 2*BB*HH)     // 3,265,536
#define OFF_COPY    (OFF_ATTN + BB*TT)         // 3,291,136
#define OFF_NEWCOV  (OFF_COPY + BB*VV)         // 6,491,136
#define OFF_LOSS    (OFF_NEWCOV + BB*TT)       // 6,516,736

// ---- workspace layout (floats) ----
#define WS_H0     0
#define WS_S      (WS_H0 + BB*HH)
#define WS_SDOT   (WS_S + BB*HH)
#define WS_CC     (WS_SDOT + 64)
#define WS_TS     (WS_CC + 64)
#define WS_ATTN   (WS_TS + BB*TT)
#define WS_LOSSP  (WS_ATTN + BB*TT)
#define WS_CTXP   (WS_LOSSP + 64)
#define WS_CTX    (WS_CTXP + BB*4*HH)
#define WS_NI     (WS_CTX + BB*HH)
#define WS_PGEN   (WS_NI + BB*H4)
#define WS_LOGITS (WS_PGEN + 64)
#define WS_RM     (WS_LOGITS + BB*VV)
#define WS_RS     (WS_RM + 64)
// total ~3.55M floats = ~14.2 MB of d_ws

__device__ __forceinline__ float wredsum(float v) {
#pragma unroll
  for (int o = 32; o > 0; o >>= 1) v += __shfl_down(v, o, 64);
  return v;
}
__device__ __forceinline__ float wredmax(float v) {
#pragma unroll
  for (int o = 32; o > 0; o >>= 1) v = fmaxf(v, __shfl_down(v, o, 64));
  return v;
}
__device__ __forceinline__ float dot4(float4 a, float4 b) {
  return a.x*b.x + a.y*b.y + a.z*b.z + a.w*b.w;
}
__device__ __forceinline__ float sigmoidf(float x) { return 1.f / (1.f + expf(-x)); }

// ---------------- zero copy_prob region ----------------
__global__ void zero_kernel(float* __restrict__ p) {
  int i = blockIdx.x * 256 + threadIdx.x;   // 800000 float4s
  ((float4*)p)[i] = make_float4(0.f, 0.f, 0.f, 0.f);
}

// ---------------- GRU cell (one block per batch row) ----------------
__global__ void gru_kernel(const float* __restrict__ xbase, const int* __restrict__ ids, int xdim,
                           const float* __restrict__ hprev,
                           const float* __restrict__ W_ih, const float* __restrict__ W_hh,
                           const float* __restrict__ b_ih, const float* __restrict__ b_hh,
                           float* __restrict__ hout_ws, float* __restrict__ hout_out) {
  int b = blockIdx.x;
  int j = threadIdx.x;                       // 0..511
  __shared__ float xs[HH];
  __shared__ float hs[HH];
  const float* xrow = xbase + (size_t)(ids ? ids[b] : b) * xdim;
  if (j < xdim) xs[j] = xrow[j];
  hs[j] = hprev[b * HH + j];
  __syncthreads();

  float gi_r = 0.f, gi_z = 0.f, gi_n = 0.f;
  const float* wr = W_ih + (size_t)j * xdim;
  const float* wz = W_ih + (size_t)(HH + j) * xdim;
  const float* wn = W_ih + (size_t)(2 * HH + j) * xdim;
  for (int k = 0; k < xdim; k += 4) {
    float4 xv = *(const float4*)&xs[k];
    gi_r += dot4(*(const float4*)&wr[k], xv);
    gi_z += dot4(*(const float4*)&wz[k], xv);
    gi_n += dot4(*(const float4*)&wn[k], xv);
  }
  float gh_r = 0.f, gh_z = 0.f, gh_n = 0.f;
  const float* vr = W_hh + (size_t)j * HH;
  const float* vz = W_hh + (size_t)(HH + j) * HH;
  const float* vn = W_hh + (size_t)(2 * HH + j) * HH;
  for (int k = 0; k < HH; k += 4) {
    float4 hv = *(const float4*)&hs[k];
    gh_r += dot4(*(const float4*)&vr[k], hv);
    gh_z += dot4(*(const float4*)&vz[k], hv);
    gh_n += dot4(*(const float4*)&vn[k], hv);
  }
  float r = sigmoidf(gi_r + b_ih[j]        + gh_r + b_hh[j]);
  float z = sigmoidf(gi_z + b_ih[HH + j]   + gh_z + b_hh[HH + j]);
  float n = tanhf  (gi_n + b_ih[2*HH + j] + r * (gh_n + b_hh[2*HH + j]));
  float h = (1.f - z) * n + z * hs[j];
  hout_ws[b * HH + j] = h;
  hout_out[b * HH + j] = h;
}

// ---------------- sdot[b] = s[b]·aW[512:1024], and c1/c0 constants ----------------
__global__ void sdot_kernel(const float* __restrict__ s, const float* __restrict__ aW,
                            const float* __restrict__ ab, const float* __restrict__ covW,
                            const float* __restrict__ covb, float* __restrict__ sdot,
                            float* __restrict__ cc) {
  int wid = threadIdx.x >> 6, lane = threadIdx.x & 63;
  int b = blockIdx.x * 4 + wid;
  float d = 0.f;
  const float* sp = s + (size_t)b * HH + lane * 8;
  const float* ap = aW + HH + lane * 8;
  d += dot4(*(const float4*)&sp[0], *(const float4*)&ap[0]);
  d += dot4(*(const float4*)&sp[4], *(const float4*)&ap[4]);
  d = wredsum(d);
  if (lane == 0) sdot[b] = d;
  if (blockIdx.x == 0 && wid == 0) {
    float c1 = 0.f, c0 = 0.f;
#pragma unroll
    for (int i = 0; i < 8; i++) {
      int idx = lane * 8 + i;
      float a2 = aW[2 * HH + idx];
      c1 += covW[idx] * a2;
      c0 += covb[idx] * a2;
    }
    c1 = wredsum(c1);
    c0 = wredsum(c0);
    if (lane == 0) { cc[0] = c1; cc[1] = c0 + ab[0]; }
  }
}

// ---------------- tanh(scores): one wave per (b,t) ----------------
__global__ void scores_kernel(const float* __restrict__ enc, const float* __restrict__ cov,
                              const float* __restrict__ aW, const float* __restrict__ sdot,
                              const float* __restrict__ cc, float* __restrict__ ts) {
  int b = blockIdx.y;
  int wid = threadIdx.x >> 6, lane = threadIdx.x & 63;
  int t = blockIdx.x * 4 + wid;
  const float* e = enc + ((size_t)b * TT + t) * HH + lane * 8;
  const float* a = aW + lane * 8;
  float d = dot4(*(const float4*)&e[0], *(const float4*)&a[0])
          + dot4(*(const float4*)&e[4], *(const float4*)&a[4]);
  d = wredsum(d);
  if (lane == 0) {
    float sc = d + sdot[b] + cov[b * TT + t] * cc[0] + cc[1];
    ts[b * TT + t] = tanhf(sc);
  }
}

// ---------------- attention softmax over T, new_coverage, per-b loss ----------------
__global__ void attn_kernel(const float* __restrict__ ts, const float* __restrict__ cov,
                            float* __restrict__ wattn, float* __restrict__ dout,
                            float* __restrict__ lossp) {
  int b = blockIdx.x, tid = threadIdx.x;
  int lane = tid & 63, wid = tid >> 6;
  __shared__ float sred[8];
  __shared__ float bval[2];
  float v = (tid < TT) ? ts[b * TT + tid] : -1e30f;
  float wm = wredmax(v);
  if (lane == 0) sred[wid] = wm;
  __syncthreads();
  if (wid == 0) {
    float r = (lane < 8) ? sred[lane] : -1e30f;
    r = wredmax(r);
    if (lane == 0) bval[0] = r;
  }
  __syncthreads();
  float m = bval[0];
  float e = (tid < TT) ? expf(v - m) : 0.f;
  float wsm = wredsum(e);
  __syncthreads();
  if (lane == 0) sred[wid] = wsm;
  __syncthreads();
  if (wid == 0) {
    float r = (lane < 8) ? sred[lane] : 0.f;
    r = wredsum(r);
    if (lane == 0) bval[1] = r;
  }
  __syncthreads();
  float denom = bval[1];
  float a = e / denom;
  float lp = 0.f;
  if (tid < TT) {
    wattn[b * TT + tid] = a;
    dout[OFF_ATTN + b * TT + tid] = a;
    float c = cov[b * TT + tid];
    dout[OFF_NEWCOV + b * TT + tid] = c + a;
    lp = fminf(a, c);
  }
  float wl = wredsum(lp);
  __syncthreads();
  if (lane == 0) sred[wid] = wl;
  __syncthreads();
  if (wid == 0) {
    float r = (lane < 8) ? sred[lane] : 0.f;
    r = wredsum(r);
    if (lane == 0) lossp[b] = r;
  }
}

// ---------------- scatter copy_prob ----------------
__global__ void scatter_kernel(const float* __restrict__ attn, const int* __restrict__ src,
                               float* __restrict__ outc) {
  int i = blockIdx.x * 256 + threadIdx.x;     // 25600
  if (i < BB * TT) {
    int b = i / TT;
    atomicAdd(&outc[(size_t)b * VV + src[i]], attn[i]);
  }
}

// ---------------- coverage loss final ----------------
__global__ void loss_kernel(const float* __restrict__ lossp, float* __restrict__ dst) {
  float v = lossp[threadIdx.x];
  v = wredsum(v);
  if (threadIdx.x == 0) dst[0] = v;
}

// ---------------- context partials: (b, t-chunk) ----------------
__global__ void ctx_kernel(const float* __restrict__ enc, const float* __restrict__ attn,
                           float* __restrict__ ctxp) {
  int b = blockIdx.x, c = blockIdx.y;
  int h = threadIdx.x;
  __shared__ float as[100];
  if (h < 100) as[h] = attn[b * TT + c * 100 + h];
  __syncthreads();
  const float* e = enc + ((size_t)b * TT + c * 100) * HH + h;
  float acc = 0.f;
  for (int t = 0; t < 100; t++) acc += as[t] * e[(size_t)t * HH];
  ctxp[((size_t)b * 4 + c) * HH + h] = acc;
}

__global__ void ctxred_kernel(const float* __restrict__ ctxp, float* __restrict__ ctx) {
  int b = blockIdx.x, h = threadIdx.x;
  float acc = 0.f;
#pragma unroll
  for (int c = 0; c < 4; c++) acc += ctxp[((size_t)b * 4 + c) * HH + h];
  ctx[b * HH + h] = acc;
}

// ---------------- p_gen: one wave per b ----------------
__global__ void pgen_kernel(const float* __restrict__ ctx, const float* __restrict__ s,
                            const float* __restrict__ embt, const int* __restrict__ ids,
                            const float* __restrict__ gW, const float* __restrict__ gb,
                            float* __restrict__ pgen) {
  int wid = threadIdx.x >> 6, lane = threadIdx.x & 63;
  int b = blockIdx.x * 8 + wid;
  const float* erow = embt + (size_t)ids[b] * EE;
  float d = 0.f;
#pragma unroll
  for (int i = 0; i < 18; i++) {
    int idx = i * 64 + lane;                  // 1152 = 18*64
    float g = (idx < HH) ? ctx[b * HH + idx]
            : (idx < 2 * HH) ? s[b * HH + idx - HH]
            : erow[idx - 2 * HH];
    d += g * gW[idx];
  }
  d = wredsum(d);
  if (lane == 0) pgen[b] = sigmoidf(d + gb[0]);
}

// ---------------- fc1: ni = tanh([s,ctx] @ W^T + b) ----------------
__global__ void fc1_kernel(const float* __restrict__ s, const float* __restrict__ ctx,
                           const float* __restrict__ W, const float* __restrict__ bias,
                           float* __restrict__ ni) {
  int b = blockIdx.x >> 2;
  int k = (blockIdx.x & 3) * 256 + threadIdx.x;
  __shared__ float in[H4];
#pragma unroll
  for (int q = 0; q < 4; q++) {
    int i = q * 256 + threadIdx.x;
    in[i] = (i < HH) ? s[b * HH + i] : ctx[b * HH + i - HH];
  }
  __syncthreads();
  const float* w = W + (size_t)k * H4;
  float acc = 0.f;
  for (int i = 0; i < H4; i += 4)
    acc += dot4(*(const float4*)&w[i], *(const float4*)&in[i]);
  ni[(size_t)b * H4 + k] = tanhf(acc + bias[k]);
}

// ---------------- fc2: logits = ni @ W^T + b  (64 x 50000, K=1024) ----------------
__global__ __launch_bounds__(256) void fc2_kernel(const float* __restrict__ ni,
                                                  const float* __restrict__ W,
                                                  const float* __restrict__ bias,
                                                  float* __restrict__ logits) {
  __shared__ float nil[32][68];
  __shared__ float wl[32][140];
  const int tid = threadIdx.x;
  const int v0 = blockIdx.x * 128;
  const int tb = tid >> 4;                    // 16 b-groups of 4
  const int tv = tid & 15;                    // 16 v-groups of 8
  const int wc = tv * 8 + ((tv >> 2) << 2);   // bank-despread column
  float acc[4][8];
#pragma unroll
  for (int i = 0; i < 4; i++)
#pragma unroll
    for (int j = 0; j < 8; j++) acc[i][j] = 0.f;

  for (int k0 = 0; k0 < H4; k0 += 32) {
    __syncthreads();
#pragma unroll
    for (int q = 0; q < 2; q++) {             // stage ni chunk (64b x 32k), transposed
      int fi = q * 256 + tid;
      int bb = fi >> 3, kq = fi & 7;
      float4 x = *(const float4*)&ni[(size_t)bb * H4 + k0 + kq * 4];
      nil[kq*4+0][bb] = x.x; nil[kq*4+1][bb] = x.y;
      nil[kq*4+2][bb] = x.z; nil[kq*4+3][bb] = x.w;
    }
#pragma unroll
    for (int q = 0; q < 4; q++) {             // stage W chunk (128v x 32k), transposed+swizzled
      int fi = q * 256 + tid;
      int vv = fi >> 3, kq = fi & 7;
      int v = v0 + vv;
      float4 x = make_float4(0.f, 0.f, 0.f, 0.f);
      if (v < VV) x = *(const float4*)&W[(size_t)v * H4 + k0 + kq * 4];
      int vs = vv + ((vv >> 5) << 2);
      wl[kq*4+0][vs] = x.x; wl[kq*4+1][vs] = x.y;
      wl[kq*4+2][vs] = x.z; wl[kq*4+3][vs] = x.w;
    }
    __syncthreads();
#pragma unroll 8
    for (int kk = 0; kk < 32; kk++) {
      float4 a  = *(const float4*)&nil[kk][tb << 2];
      float4 w0 = *(const float4*)&wl[kk][wc];
      float4 w1 = *(const float4*)&wl[kk][wc + 4];
      float av[4] = {a.x, a.y, a.z, a.w};
      float wv[8] = {w0.x, w0.y, w0.z, w0.w, w1.x, w1.y, w1.z, w1.w};
#pragma unroll
      for (int i = 0; i < 4; i++)
#pragma unroll
        for (int j = 0; j < 8; j++) acc[i][j] += av[i] * wv[j];
    }
  }
  int vbase = v0 + tv * 8;
  if (vbase < VV) {                            // V % 8 == 0, whole group in-bounds
    float bv[8];
#pragma unroll
    for (int j = 0; j < 8; j++) bv[j] = bias[vbase + j];
#pragma unroll
    for (int i = 0; i < 4; i++) {
      int b = tb * 4 + i;
      float4 o0 = make_float4(acc[i][0]+bv[0], acc[i][1]+bv[1], acc[i][2]+bv[2], acc[i][3]+bv[3]);
      float4 o1 = make_float4(acc[i][4]+bv[4], acc[i][5]+bv[5], acc[i][6]+bv[6], acc[i][7]+bv[7]);
      *(float4*)&logits[(size_t)b * VV + vbase]     = o0;
      *(float4*)&logits[(size_t)b * VV + vbase + 4] = o1;
    }
  }
}

// ---------------- per-row vocab softmax stats ----------------
__global__ void smax_kernel(const float* __restrict__ logits, float* __restrict__ rm,
                            float* __restrict__ rs) {
  int b = blockIdx.x, tid = threadIdx.x;
  int lane = tid & 63, wid = tid >> 6;
  __shared__ float sred[4];
  __shared__ float bval[2];
  const float4* row = (const float4*)(logits + (size_t)b * VV);
  float m = -1e30f;
  for (int i = tid; i < VV / 4; i += 256) {
    float4 l = row[i];
    m = fmaxf(m, fmaxf(fmaxf(l.x, l.y), fmaxf(l.z, l.w)));
  }
  m = wredmax(m);
  if (lane == 0) sred[wid] = m;
  __syncthreads();
  if (wid == 0) {
    float r = (lane < 4) ? sred[lane] : -1e30f;
    r = wredmax(r);
    if (lane == 0) bval[0] = r;
  }
  __syncthreads();
  float bm = bval[0];
  float sacc = 0.f;
  for (int i = tid; i < VV / 4; i += 256) {
    float4 l = row[i];
    sacc += expf(l.x - bm) + expf(l.y - bm) + expf(l.z - bm) + expf(l.w - bm);
  }
  sacc = wredsum(sacc);
  __syncthreads();
  if (lane == 0) sred[wid] = sacc;
  __syncthreads();
  if (wid == 0) {
    float r = (lane < 4) ? sred[lane] : 0.f;
    r = wredsum(r);
    if (lane == 0) { rm[b] = bm; rs[b] = r; }
  }
}

// ---------------- final mix: out = Pvocab*p_gen + copy*(1-p_gen) ----------------
__global__ void final_kernel(const float* __restrict__ logits, const float* __restrict__ rm,
                             const float* __restrict__ rs, const float* __restrict__ pgen,
                             const float* __restrict__ copy, float* __restrict__ out) {
  int i = blockIdx.x * 256 + threadIdx.x;     // over 800000 float4s
  int b = (i * 4) / VV;
  float p = pgen[b], m = rm[b], s = rs[b];
  float4 l = ((const float4*)logits)[i];
  float4 c = ((const float4*)copy)[i];
  float q = 1.f - p;
  float4 o;
  o.x = expf(l.x - m) / s * p + c.x * q;
  o.y = expf(l.y - m) / s * p + c.y * q;
  o.z = expf(l.z - m) / s * p + c.z * q;
  o.w = expf(l.w - m) / s * p + c.w * q;
  ((float4*)out)[i] = o;
}

extern "C" void kernel_launch(void* const* d_in, const int* in_sizes, int n_in,
                              void* d_out, int out_size, void* d_ws, size_t ws_size,
                              hipStream_t stream) {
  const int*   ids  = (const int*)d_in[0];
  const float* preh = (const float*)d_in[1];
  const float* enc  = (const float*)d_in[2];
  const int*   src  = (const int*)d_in[3];
  const float* cov  = (const float*)d_in[4];
  const float* embt = (const float*)d_in[5];
  const float* Wih0 = (const float*)d_in[6];
  const float* Whh0 = (const float*)d_in[7];
  const float* bih0 = (const float*)d_in[8];
  const float* bhh0 = (const float*)d_in[9];
  const float* Wih1 = (const float*)d_in[10];
  const float* Whh1 = (const float*)d_in[11];
  const float* bih1 = (const float*)d_in[12];
  const float* bhh1 = (const float*)d_in[13];
  const float* aW   = (const float*)d_in[14];
  const float* ab   = (const float*)d_in[15];
  const float* covW = (const float*)d_in[16];
  const float* covb = (const float*)d_in[17];
  const float* f1W  = (const float*)d_in[18];
  const float* f1b  = (const float*)d_in[19];
  const float* f2W  = (const float*)d_in[20];
  const float* f2b  = (const float*)d_in[21];
  const float* gW   = (const float*)d_in[22];
  const float* gb   = (const float*)d_in[23];
  float* out = (float*)d_out;
  float* ws  = (float*)d_ws;

  zero_kernel<<<3125, 256, 0, stream>>>(out + OFF_COPY);
  gru_kernel<<<64, 512, 0, stream>>>(embt, ids, EE, preh, Wih0, Whh0, bih0, bhh0,
                                     ws + WS_H0, out + OFF_CURHID);
  gru_kernel<<<64, 512, 0, stream>>>(ws + WS_H0, nullptr, HH, preh + BB * HH, Wih1, Whh1,
                                     bih1, bhh1, ws + WS_S, out + OFF_CURHID + BB * HH);
  sdot_kernel<<<16, 256, 0, stream>>>(ws + WS_S, aW, ab, covW, covb, ws + WS_SDOT, ws + WS_CC);
  scores_kernel<<<dim3(100, 64), 256, 0, stream>>>(enc, cov, aW, ws + WS_SDOT, ws + WS_CC,
                                                   ws + WS_TS);
  attn_kernel<<<64, 512, 0, stream>>>(ws + WS_TS, cov, ws + WS_ATTN, out, ws + WS_LOSSP);
  scatter_kernel<<<100, 256, 0, stream>>>(ws + WS_ATTN, src, out + OFF_COPY);
  loss_kernel<<<1, 64, 0, stream>>>(ws + WS_LOSSP, out + OFF_LOSS);
  ctx_kernel<<<dim3(64, 4), 512, 0, stream>>>(enc, ws + WS_ATTN, ws + WS_CTXP);
  ctxred_kernel<<<64, 512, 0, stream>>>(ws + WS_CTXP, ws + WS_CTX);
  pgen_kernel<<<8, 512, 0, stream>>>(ws + WS_CTX, ws + WS_S, embt, ids, gW, gb, ws + WS_PGEN);
  fc1_kernel<<<256, 256, 0, stream>>>(ws + WS_S, ws + WS_CTX, f1W, f1b, ws + WS_NI);
  fc2_kernel<<<391, 256, 0, stream>>>(ws + WS_NI, f2W, f2b, ws + WS_LOGITS);
  smax_kernel<<<64, 256, 0, stream>>>(ws + WS_LOGITS, ws + WS_RM, ws + WS_RS);
  final_kernel<<<3125, 256, 0, stream>>>(ws + WS_LOGITS, ws + WS_RM, ws + WS_RS,
                                         ws + WS_PGEN, out + OFF_COPY, out);
}

// Round 2
// 503.475 us; speedup vs baseline: 1.1269x; 1.1269x over previous
//
#include <hip/hip_runtime.h>
#include <hip/hip_bf16.h>
#include <cstddef>

#define BB 64
#define TT 400
#define EE 128
#define HH 512
#define H4 1024
#define VV 50000

// ---- d_out layout (floats), reference return order ----
#define OFF_OUT     0
#define OFF_CURHID  (BB*VV)                    // 3,200,000
#define OFF_ATTN    (OFF_CURHID + 2*BB*HH)     // 3,265,536
#define OFF_COPY    (OFF_ATTN + BB*TT)         // 3,291,136
#define OFF_NEWCOV  (OFF_COPY + BB*VV)         // 6,491,136
#define OFF_LOSS    (OFF_NEWCOV + BB*TT)       // 6,516,736

// ---- workspace layout (floats) ----
#define WS_H0     0
#define WS_S      (WS_H0 + BB*HH)
#define WS_TS     (WS_S + BB*HH)
#define WS_ATTN   (WS_TS + BB*TT)
#define WS_CTX    (WS_ATTN + BB*TT)
#define WS_NI     (WS_CTX + BB*HH)             // holds bf16 ni (64x1024 ushorts)
#define WS_PGEN   (WS_NI + BB*H4)
#define WS_LOGITS (WS_PGEN + 64)
#define WS_RM     (WS_LOGITS + BB*VV)
#define WS_RS     (WS_RM + 64)

typedef __attribute__((ext_vector_type(8))) short short8v;
typedef __attribute__((ext_vector_type(4))) float f32x4;

__device__ __forceinline__ float wredsum(float v) {
#pragma unroll
  for (int o = 32; o > 0; o >>= 1) v += __shfl_down(v, o, 64);
  return v;
}
__device__ __forceinline__ float wredmax(float v) {
#pragma unroll
  for (int o = 32; o > 0; o >>= 1) v = fmaxf(v, __shfl_down(v, o, 64));
  return v;
}
__device__ __forceinline__ float dot4(float4 a, float4 b) {
  return a.x*b.x + a.y*b.y + a.z*b.z + a.w*b.w;
}
__device__ __forceinline__ float sigmoidf(float x) { return 1.f / (1.f + expf(-x)); }
__device__ __forceinline__ short bfh(float f) {
  union { __hip_bfloat16 h; short s; } u; u.h = __float2bfloat16(f); return u.s;
}

// ---------------- zero copy_prob region + loss slot ----------------
__global__ void zero_kernel(float* __restrict__ p, float* __restrict__ loss) {
  int i = blockIdx.x * 256 + threadIdx.x;   // 800000 float4s
  ((float4*)p)[i] = make_float4(0.f, 0.f, 0.f, 0.f);
  if (i == 0) loss[0] = 0.f;
}

// ---------------- GRU cell (one block per batch row) ----------------
__global__ void gru_kernel(const float* __restrict__ xbase, const int* __restrict__ ids, int xdim,
                           const float* __restrict__ hprev,
                           const float* __restrict__ W_ih, const float* __restrict__ W_hh,
                           const float* __restrict__ b_ih, const float* __restrict__ b_hh,
                           float* __restrict__ hout_ws, float* __restrict__ hout_out) {
  int b = blockIdx.x;
  int j = threadIdx.x;                       // 0..511
  __shared__ float xs[HH];
  __shared__ float hs[HH];
  const float* xrow = xbase + (size_t)(ids ? ids[b] : b) * xdim;
  if (j < xdim) xs[j] = xrow[j];
  hs[j] = hprev[b * HH + j];
  __syncthreads();

  float gi_r = 0.f, gi_z = 0.f, gi_n = 0.f;
  const float* wr = W_ih + (size_t)j * xdim;
  const float* wz = W_ih + (size_t)(HH + j) * xdim;
  const float* wn = W_ih + (size_t)(2 * HH + j) * xdim;
  for (int k = 0; k < xdim; k += 4) {
    float4 xv = *(const float4*)&xs[k];
    gi_r += dot4(*(const float4*)&wr[k], xv);
    gi_z += dot4(*(const float4*)&wz[k], xv);
    gi_n += dot4(*(const float4*)&wn[k], xv);
  }
  float gh_r = 0.f, gh_z = 0.f, gh_n = 0.f;
  const float* vr = W_hh + (size_t)j * HH;
  const float* vz = W_hh + (size_t)(HH + j) * HH;
  const float* vn = W_hh + (size_t)(2 * HH + j) * HH;
  for (int k = 0; k < HH; k += 4) {
    float4 hv = *(const float4*)&hs[k];
    gh_r += dot4(*(const float4*)&vr[k], hv);
    gh_z += dot4(*(const float4*)&vz[k], hv);
    gh_n += dot4(*(const float4*)&vn[k], hv);
  }
  float r = sigmoidf(gi_r + b_ih[j]        + gh_r + b_hh[j]);
  float z = sigmoidf(gi_z + b_ih[HH + j]   + gh_z + b_hh[HH + j]);
  float n = tanhf  (gi_n + b_ih[2*HH + j] + r * (gh_n + b_hh[2*HH + j]));
  float h = (1.f - z) * n + z * hs[j];
  hout_ws[b * HH + j] = h;
  hout_out[b * HH + j] = h;
}

// ---------------- tanh(scores): one wave per (b,t); sdot/cc fused in ----------------
__global__ void scores_kernel(const float* __restrict__ enc, const float* __restrict__ cov,
                              const float* __restrict__ aW, const float* __restrict__ ab,
                              const float* __restrict__ covW, const float* __restrict__ covb,
                              const float* __restrict__ s, float* __restrict__ ts) {
  int b = blockIdx.y;
  int wid = threadIdx.x >> 6, lane = threadIdx.x & 63;
  int t = blockIdx.x * 4 + wid;
  int i8 = lane * 8;
  const float* e = enc + ((size_t)b * TT + t) * HH + i8;
  float4 a0 = *(const float4*)&aW[i8],        a1 = *(const float4*)&aW[i8 + 4];
  float4 b0 = *(const float4*)&aW[HH + i8],   b1 = *(const float4*)&aW[HH + i8 + 4];
  float4 c0 = *(const float4*)&aW[2*HH + i8], c1 = *(const float4*)&aW[2*HH + i8 + 4];
  float4 s0 = *(const float4*)&s[(size_t)b * HH + i8], s1 = *(const float4*)&s[(size_t)b * HH + i8 + 4];
  float4 w0 = *(const float4*)&covW[i8],      w1 = *(const float4*)&covW[i8 + 4];
  float4 v0 = *(const float4*)&covb[i8],      v1 = *(const float4*)&covb[i8 + 4];
  float covbt = cov[b * TT + t];
  // p1 = e·aW0 + s·aW1 + covb·aW2 ; p2 = covW·aW2 (scaled by cov scalar)
  float p1 = dot4(*(const float4*)&e[0], a0) + dot4(*(const float4*)&e[4], a1)
           + dot4(s0, b0) + dot4(s1, b1)
           + dot4(v0, c0) + dot4(v1, c1);
  float p2 = dot4(w0, c0) + dot4(w1, c1);
  float d = wredsum(p1 + covbt * p2);
  if (lane == 0) ts[b * TT + t] = tanhf(d + ab[0]);
}

// ---------------- attention softmax over T + new_coverage + scatter + loss ----------------
__global__ void attn_kernel(const float* __restrict__ ts, const float* __restrict__ cov,
                            const int* __restrict__ src,
                            float* __restrict__ wattn, float* __restrict__ dout,
                            float* __restrict__ outc) {
  int b = blockIdx.x, tid = threadIdx.x;
  int lane = tid & 63, wid = tid >> 6;
  __shared__ float sred[8];
  __shared__ float bval[2];
  float v = (tid < TT) ? ts[b * TT + tid] : -1e30f;
  float wm = wredmax(v);
  if (lane == 0) sred[wid] = wm;
  __syncthreads();
  if (wid == 0) {
    float r = (lane < 8) ? sred[lane] : -1e30f;
    r = wredmax(r);
    if (lane == 0) bval[0] = r;
  }
  __syncthreads();
  float m = bval[0];
  float e = (tid < TT) ? expf(v - m) : 0.f;
  float wsm = wredsum(e);
  __syncthreads();
  if (lane == 0) sred[wid] = wsm;
  __syncthreads();
  if (wid == 0) {
    float r = (lane < 8) ? sred[lane] : 0.f;
    r = wredsum(r);
    if (lane == 0) bval[1] = r;
  }
  __syncthreads();
  float denom = bval[1];
  float a = e / denom;
  float lp = 0.f;
  if (tid < TT) {
    wattn[b * TT + tid] = a;
    dout[OFF_ATTN + b * TT + tid] = a;
    float c = cov[b * TT + tid];
    dout[OFF_NEWCOV + b * TT + tid] = c + a;
    lp = fminf(a, c);
    atomicAdd(&outc[(size_t)b * VV + src[b * TT + tid]], a);
  }
  float wl = wredsum(lp);
  __syncthreads();
  if (lane == 0) sred[wid] = wl;
  __syncthreads();
  if (wid == 0) {
    float r = (lane < 8) ? sred[lane] : 0.f;
    r = wredsum(r);
    if (lane == 0) atomicAdd(&dout[OFF_LOSS], r);
  }
}

// ---------------- context + p_gen fused: one block per b ----------------
__global__ void ctxpgen_kernel(const float* __restrict__ enc, const float* __restrict__ attn,
                               const float* __restrict__ s, const float* __restrict__ embt,
                               const int* __restrict__ ids, const float* __restrict__ gW,
                               const float* __restrict__ gb,
                               float* __restrict__ ctx, float* __restrict__ pgen) {
  int b = blockIdx.x, tid = threadIdx.x;     // 512 threads
  int lane = tid & 63, wid = tid >> 6;
  __shared__ float as[TT];
  __shared__ float sred[8];
  if (tid < TT) as[tid] = attn[b * TT + tid];
  __syncthreads();
  const float* e = enc + (size_t)b * TT * HH + tid;
  float acc = 0.f;
#pragma unroll 8
  for (int t = 0; t < TT; t++) acc += as[t] * e[(size_t)t * HH];
  ctx[b * HH + tid] = acc;
  // p_gen partial: ctx·gW[0:512] + s·gW[512:1024] + emb·gW[1024:1152]
  float part = acc * gW[tid] + s[b * HH + tid] * gW[HH + tid];
  if (tid < EE) part += embt[(size_t)ids[b] * EE + tid] * gW[2 * HH + tid];
  float w = wredsum(part);
  if (lane == 0) sred[wid] = w;
  __syncthreads();
  if (wid == 0) {
    float r = (lane < 8) ? sred[lane] : 0.f;
    r = wredsum(r);
    if (lane == 0) pgen[b] = sigmoidf(r + gb[0]);
  }
}

// ---------------- fc1: ni = tanh([s,ctx] @ W^T + b), output bf16 ----------------
__global__ void fc1_kernel(const float* __restrict__ s, const float* __restrict__ ctx,
                           const float* __restrict__ W, const float* __restrict__ bias,
                           short* __restrict__ nib) {
  int b = blockIdx.x >> 2;
  int k = (blockIdx.x & 3) * 256 + threadIdx.x;
  __shared__ float in[H4];
#pragma unroll
  for (int q = 0; q < 4; q++) {
    int i = q * 256 + threadIdx.x;
    in[i] = (i < HH) ? s[b * HH + i] : ctx[b * HH + i - HH];
  }
  __syncthreads();
  const float* w = W + (size_t)k * H4;
  float acc = 0.f;
  for (int i = 0; i < H4; i += 4)
    acc += dot4(*(const float4*)&w[i], *(const float4*)&in[i]);
  nib[(size_t)b * H4 + k] = bfh(tanhf(acc + bias[k]));
}

// ---------------- fc2 via MFMA bf16: logits[64][50000] = ni @ W^T + b ----------------
// One wave per 16-vocab-column fragment; no LDS. B-fragments loaded straight
// from global (f32 W, converted inline); A-fragments from bf16 ni (L2-hot).
__global__ __launch_bounds__(256) void fc2_kernel(const short* __restrict__ nib,
                                                  const float* __restrict__ W,
                                                  const float* __restrict__ bias,
                                                  float* __restrict__ logits) {
  int nf = blockIdx.x * 4 + (threadIdx.x >> 6);
  if (nf >= VV / 16) return;
  int lane = threadIdx.x & 63;
  int r16 = lane & 15;                 // m-row (A) / n-col (B) index
  int kg = lane >> 4;                  // k-octet index
  int v0 = nf * 16;

  f32x4 acc0 = {0.f,0.f,0.f,0.f}, acc1 = {0.f,0.f,0.f,0.f};
  f32x4 acc2 = {0.f,0.f,0.f,0.f}, acc3 = {0.f,0.f,0.f,0.f};

  const float* wp = W + (size_t)(v0 + r16) * H4 + kg * 8;
  const short* ap = nib + (size_t)r16 * H4 + kg * 8;

#pragma unroll 2
  for (int k0 = 0; k0 < H4; k0 += 32) {
    float4 w0 = *(const float4*)&wp[k0];
    float4 w1 = *(const float4*)&wp[k0 + 4];
    short8v bf;
    bf[0] = bfh(w0.x); bf[1] = bfh(w0.y); bf[2] = bfh(w0.z); bf[3] = bfh(w0.w);
    bf[4] = bfh(w1.x); bf[5] = bfh(w1.y); bf[6] = bfh(w1.z); bf[7] = bfh(w1.w);
    short8v a0 = *(const short8v*)&ap[k0];
    short8v a1 = *(const short8v*)&ap[16 * H4 + k0];
    short8v a2 = *(const short8v*)&ap[32 * H4 + k0];
    short8v a3 = *(const short8v*)&ap[48 * H4 + k0];
    acc0 = __builtin_amdgcn_mfma_f32_16x16x32_bf16(a0, bf, acc0, 0, 0, 0);
    acc1 = __builtin_amdgcn_mfma_f32_16x16x32_bf16(a1, bf, acc1, 0, 0, 0);
    acc2 = __builtin_amdgcn_mfma_f32_16x16x32_bf16(a2, bf, acc2, 0, 0, 0);
    acc3 = __builtin_amdgcn_mfma_f32_16x16x32_bf16(a3, bf, acc3, 0, 0, 0);
  }

  float bv = bias[v0 + r16];
  size_t col = (size_t)v0 + r16;
  int rbase = kg * 4;                  // C/D: row = (lane>>4)*4 + reg
#pragma unroll
  for (int r = 0; r < 4; r++) {
    logits[(size_t)(rbase + r) * VV + col]      = acc0[r] + bv;
    logits[(size_t)(16 + rbase + r) * VV + col] = acc1[r] + bv;
    logits[(size_t)(32 + rbase + r) * VV + col] = acc2[r] + bv;
    logits[(size_t)(48 + rbase + r) * VV + col] = acc3[r] + bv;
  }
}

// ---------------- per-row vocab softmax stats ----------------
__global__ void smax_kernel(const float* __restrict__ logits, float* __restrict__ rm,
                            float* __restrict__ rs) {
  int b = blockIdx.x, tid = threadIdx.x;
  int lane = tid & 63, wid = tid >> 6;
  __shared__ float sred[4];
  __shared__ float bval[2];
  const float4* row = (const float4*)(logits + (size_t)b * VV);
  float m = -1e30f;
  for (int i = tid; i < VV / 4; i += 256) {
    float4 l = row[i];
    m = fmaxf(m, fmaxf(fmaxf(l.x, l.y), fmaxf(l.z, l.w)));
  }
  m = wredmax(m);
  if (lane == 0) sred[wid] = m;
  __syncthreads();
  if (wid == 0) {
    float r = (lane < 4) ? sred[lane] : -1e30f;
    r = wredmax(r);
    if (lane == 0) bval[0] = r;
  }
  __syncthreads();
  float bm = bval[0];
  float sacc = 0.f;
  for (int i = tid; i < VV / 4; i += 256) {
    float4 l = row[i];
    sacc += expf(l.x - bm) + expf(l.y - bm) + expf(l.z - bm) + expf(l.w - bm);
  }
  sacc = wredsum(sacc);
  __syncthreads();
  if (lane == 0) sred[wid] = sacc;
  __syncthreads();
  if (wid == 0) {
    float r = (lane < 4) ? sred[lane] : 0.f;
    r = wredsum(r);
    if (lane == 0) { rm[b] = bm; rs[b] = r; }
  }
}

// ---------------- final mix: out = Pvocab*p_gen + copy*(1-p_gen) ----------------
__global__ void final_kernel(const float* __restrict__ logits, const float* __restrict__ rm,
                             const float* __restrict__ rs, const float* __restrict__ pgen,
                             const float* __restrict__ copy, float* __restrict__ out) {
  int i = blockIdx.x * 256 + threadIdx.x;     // over 800000 float4s
  int b = (i * 4) / VV;
  float p = pgen[b], m = rm[b], s = rs[b];
  float4 l = ((const float4*)logits)[i];
  float4 c = ((const float4*)copy)[i];
  float q = 1.f - p;
  float4 o;
  o.x = expf(l.x - m) / s * p + c.x * q;
  o.y = expf(l.y - m) / s * p + c.y * q;
  o.z = expf(l.z - m) / s * p + c.z * q;
  o.w = expf(l.w - m) / s * p + c.w * q;
  ((float4*)out)[i] = o;
}

extern "C" void kernel_launch(void* const* d_in, const int* in_sizes, int n_in,
                              void* d_out, int out_size, void* d_ws, size_t ws_size,
                              hipStream_t stream) {
  const int*   ids  = (const int*)d_in[0];
  const float* preh = (const float*)d_in[1];
  const float* enc  = (const float*)d_in[2];
  const int*   src  = (const int*)d_in[3];
  const float* cov  = (const float*)d_in[4];
  const float* embt = (const float*)d_in[5];
  const float* Wih0 = (const float*)d_in[6];
  const float* Whh0 = (const float*)d_in[7];
  const float* bih0 = (const float*)d_in[8];
  const float* bhh0 = (const float*)d_in[9];
  const float* Wih1 = (const float*)d_in[10];
  const float* Whh1 = (const float*)d_in[11];
  const float* bih1 = (const float*)d_in[12];
  const float* bhh1 = (const float*)d_in[13];
  const float* aW   = (const float*)d_in[14];
  const float* ab   = (const float*)d_in[15];
  const float* covW = (const float*)d_in[16];
  const float* covb = (const float*)d_in[17];
  const float* f1W  = (const float*)d_in[18];
  const float* f1b  = (const float*)d_in[19];
  const float* f2W  = (const float*)d_in[20];
  const float* f2b  = (const float*)d_in[21];
  const float* gW   = (const float*)d_in[22];
  const float* gb   = (const float*)d_in[23];
  float* out = (float*)d_out;
  float* ws  = (float*)d_ws;

  zero_kernel<<<3125, 256, 0, stream>>>(out + OFF_COPY, out + OFF_LOSS);
  gru_kernel<<<64, 512, 0, stream>>>(embt, ids, EE, preh, Wih0, Whh0, bih0, bhh0,
                                     ws + WS_H0, out + OFF_CURHID);
  gru_kernel<<<64, 512, 0, stream>>>(ws + WS_H0, nullptr, HH, preh + BB * HH, Wih1, Whh1,
                                     bih1, bhh1, ws + WS_S, out + OFF_CURHID + BB * HH);
  scores_kernel<<<dim3(100, 64), 256, 0, stream>>>(enc, cov, aW, ab, covW, covb,
                                                   ws + WS_S, ws + WS_TS);
  attn_kernel<<<64, 512, 0, stream>>>(ws + WS_TS, cov, src, ws + WS_ATTN, out,
                                      out + OFF_COPY);
  ctxpgen_kernel<<<64, 512, 0, stream>>>(enc, ws + WS_ATTN, ws + WS_S, embt, ids, gW, gb,
                                         ws + WS_CTX, ws + WS_PGEN);
  fc1_kernel<<<256, 256, 0, stream>>>(ws + WS_S, ws + WS_CTX, f1W, f1b,
                                      (short*)(ws + WS_NI));
  fc2_kernel<<<782, 256, 0, stream>>>((const short*)(ws + WS_NI), f2W, f2b,
                                      ws + WS_LOGITS);
  smax_kernel<<<64, 256, 0, stream>>>(ws + WS_LOGITS, ws + WS_RM, ws + WS_RS);
  final_kernel<<<3125, 256, 0, stream>>>(ws + WS_LOGITS, ws + WS_RM, ws + WS_RS,
                                         ws + WS_PGEN, out + OFF_COPY, out);
}

// Round 3
// 266.325 us; speedup vs baseline: 2.1304x; 1.8905x over previous
//
#include <hip/hip_runtime.h>
#include <hip/hip_bf16.h>
#include <cstddef>

#define BB 64
#define TT 400
#define EE 128
#define HH 512
#define H4 1024
#define VV 50000

// ---- d_out layout (floats), reference return order ----
#define OFF_OUT     0
#define OFF_CURHID  (BB*VV)                    // 3,200,000
#define OFF_ATTN    (OFF_CURHID + 2*BB*HH)     // 3,265,536
#define OFF_COPY    (OFF_ATTN + BB*TT)         // 3,291,136
#define OFF_NEWCOV  (OFF_COPY + BB*VV)         // 6,491,136
#define OFF_LOSS    (OFF_NEWCOV + BB*TT)       // 6,516,736

// ---- workspace layout (floats; bf16 buffers are 2 shorts per float) ----
#define WS_S      0
#define WS_TS     (WS_S + BB*HH)               // 32768
#define WS_ATTN   (WS_TS + BB*TT)              // 58368
#define WS_CTX    (WS_ATTN + BB*TT)            // 83968
#define WS_NI     (WS_CTX + BB*HH)             // 116736 (bf16 ni, 64x1024 shorts)
#define WS_PGEN   (WS_NI + BB*H4/2)            // 149504
#define WS_RM     (WS_PGEN + 64)
#define WS_RS     (WS_RM + 64)
#define WS_AX0    (WS_RS + 64)                 // bf16 64x128
#define WS_AH0    (WS_AX0 + BB*EE/2)           // bf16 64x512
#define WS_AH1    (WS_AH0 + BB*HH/2)           // bf16 64x512
#define WS_AX1    (WS_AH1 + BB*HH/2)           // bf16 64x512 (h0)
#define WS_SB     (WS_AX1 + BB*HH/2)           // bf16 dummy sink
#define WS_LOGITS (WS_SB + BB*HH/2)            // 219328 + 3.2M

typedef __attribute__((ext_vector_type(8))) short short8v;
typedef __attribute__((ext_vector_type(4))) float f32x4;

__device__ __forceinline__ float wredsum(float v) {
#pragma unroll
  for (int o = 32; o > 0; o >>= 1) v += __shfl_down(v, o, 64);
  return v;
}
__device__ __forceinline__ float wredmax(float v) {
#pragma unroll
  for (int o = 32; o > 0; o >>= 1) v = fmaxf(v, __shfl_down(v, o, 64));
  return v;
}
__device__ __forceinline__ float dot4(float4 a, float4 b) {
  return a.x*b.x + a.y*b.y + a.z*b.z + a.w*b.w;
}
__device__ __forceinline__ float sigmoidf(float x) { return 1.f / (1.f + expf(-x)); }
__device__ __forceinline__ short bfh(float f) {
  union { __hip_bfloat16 h; short s; } u; u.h = __float2bfloat16(f); return u.s;
}

// ---------------- zero copy_prob region + loss slot ----------------
__global__ void zero_kernel(float* __restrict__ p, float* __restrict__ loss) {
  int i = blockIdx.x * 256 + threadIdx.x;   // 800000 float4s
  ((float4*)p)[i] = make_float4(0.f, 0.f, 0.f, 0.f);
  if (i == 0) loss[0] = 0.f;
}

// ---------------- prep: bf16 conversions for GRU A-operands ----------------
__global__ void prep_kernel(const float* __restrict__ embt, const int* __restrict__ ids,
                            const float* __restrict__ preh,
                            short* __restrict__ ax0, short* __restrict__ ah0,
                            short* __restrict__ ah1) {
  int tid = blockIdx.x * 256 + threadIdx.x;   // 73728 total
  if (tid < BB * EE) {
    int b = tid >> 7, k = tid & 127;
    ax0[tid] = bfh(embt[(size_t)ids[b] * EE + k]);
  } else {
    int i = tid - BB * EE;                    // 0..65535
    if (i < BB * HH) ah0[i] = bfh(preh[i]);
    else ah1[i - BB * HH] = bfh(preh[i]);
  }
}

// ---------------- GRU layer via MFMA ----------------
// Block: 3 waves (gate r/z/n), 16 hidden columns. Each wave: gi = x@W_ih^T,
// gh = h@W_hh^T for its gate over the full 64-batch, then LDS exchange and
// wave 0 applies the gating. Fragment mapping identical to validated fc2.
template<int KX>
__global__ __launch_bounds__(192) void gru_mfma_kernel(
    const short* __restrict__ Ax, const short* __restrict__ Ah,
    const float* __restrict__ W_ih, const float* __restrict__ W_hh,
    const float* __restrict__ b_ih, const float* __restrict__ b_hh,
    const float* __restrict__ hprev,
    float* __restrict__ hout_f, float* __restrict__ hout_o,
    short* __restrict__ hout_b) {
  __shared__ float R[64][16], Z[64][16], NI[64][16], NH[64][16];
  const int g = threadIdx.x >> 6;             // 0=r, 1=z, 2=n
  const int lane = threadIdx.x & 63;
  const int r16 = lane & 15, kg = lane >> 4;
  const int j0 = blockIdx.x * 16;
  const int row = g * HH + j0 + r16;          // W row = gate column

  f32x4 ai[4], ah[4];
#pragma unroll
  for (int i = 0; i < 4; i++) { ai[i] = (f32x4){0.f,0.f,0.f,0.f}; ah[i] = (f32x4){0.f,0.f,0.f,0.f}; }

  {
    const float* wp = W_ih + (size_t)row * KX + kg * 8;
    const short* ap = Ax + r16 * KX + kg * 8;
#pragma unroll
    for (int k0 = 0; k0 < KX; k0 += 32) {
      float4 w0 = *(const float4*)&wp[k0];
      float4 w1 = *(const float4*)&wp[k0 + 4];
      short8v bf;
      bf[0] = bfh(w0.x); bf[1] = bfh(w0.y); bf[2] = bfh(w0.z); bf[3] = bfh(w0.w);
      bf[4] = bfh(w1.x); bf[5] = bfh(w1.y); bf[6] = bfh(w1.z); bf[7] = bfh(w1.w);
#pragma unroll
      for (int i = 0; i < 4; i++) {
        short8v a = *(const short8v*)&ap[(size_t)i * 16 * KX + k0];
        ai[i] = __builtin_amdgcn_mfma_f32_16x16x32_bf16(a, bf, ai[i], 0, 0, 0);
      }
    }
  }
  {
    const float* wp = W_hh + (size_t)row * HH + kg * 8;
    const short* ap = Ah + r16 * HH + kg * 8;
#pragma unroll
    for (int k0 = 0; k0 < HH; k0 += 32) {
      float4 w0 = *(const float4*)&wp[k0];
      float4 w1 = *(const float4*)&wp[k0 + 4];
      short8v bf;
      bf[0] = bfh(w0.x); bf[1] = bfh(w0.y); bf[2] = bfh(w0.z); bf[3] = bfh(w0.w);
      bf[4] = bfh(w1.x); bf[5] = bfh(w1.y); bf[6] = bfh(w1.z); bf[7] = bfh(w1.w);
#pragma unroll
      for (int i = 0; i < 4; i++) {
        short8v a = *(const short8v*)&ap[(size_t)i * 16 * HH + k0];
        ah[i] = __builtin_amdgcn_mfma_f32_16x16x32_bf16(a, bf, ah[i], 0, 0, 0);
      }
    }
  }

  float bi = b_ih[row], bh = b_hh[row];
#pragma unroll
  for (int i = 0; i < 4; i++) {
#pragma unroll
    for (int r = 0; r < 4; r++) {
      int m = i * 16 + kg * 4 + r;            // batch row (C/D mapping)
      float gi = ai[i][r] + bi, gh = ah[i][r] + bh;
      if (g == 0)      R[m][r16] = sigmoidf(gi + gh);
      else if (g == 1) Z[m][r16] = sigmoidf(gi + gh);
      else             { NI[m][r16] = gi; NH[m][r16] = gh; }
    }
  }
  __syncthreads();
  if (g == 0) {
#pragma unroll
    for (int i = 0; i < 4; i++) {
#pragma unroll
      for (int r = 0; r < 4; r++) {
        int m = i * 16 + kg * 4 + r;
        int col = j0 + r16;
        float rv = R[m][r16], zv = Z[m][r16];
        float n = tanhf(NI[m][r16] + rv * NH[m][r16]);
        float hp = hprev[(size_t)m * HH + col];
        float h = (1.f - zv) * n + zv * hp;
        hout_f[(size_t)m * HH + col] = h;
        hout_o[(size_t)m * HH + col] = h;
        hout_b[(size_t)m * HH + col] = bfh(h);
      }
    }
  }
}

// ---------------- tanh(scores): one wave per (b,t); sdot/cc fused in ----------------
__global__ void scores_kernel(const float* __restrict__ enc, const float* __restrict__ cov,
                              const float* __restrict__ aW, const float* __restrict__ ab,
                              const float* __restrict__ covW, const float* __restrict__ covb,
                              const float* __restrict__ s, float* __restrict__ ts) {
  int b = blockIdx.y;
  int wid = threadIdx.x >> 6, lane = threadIdx.x & 63;
  int t = blockIdx.x * 4 + wid;
  int i8 = lane * 8;
  const float* e = enc + ((size_t)b * TT + t) * HH + i8;
  float4 a0 = *(const float4*)&aW[i8],        a1 = *(const float4*)&aW[i8 + 4];
  float4 b0 = *(const float4*)&aW[HH + i8],   b1 = *(const float4*)&aW[HH + i8 + 4];
  float4 c0 = *(const float4*)&aW[2*HH + i8], c1 = *(const float4*)&aW[2*HH + i8 + 4];
  float4 s0 = *(const float4*)&s[(size_t)b * HH + i8], s1 = *(const float4*)&s[(size_t)b * HH + i8 + 4];
  float4 w0 = *(const float4*)&covW[i8],      w1 = *(const float4*)&covW[i8 + 4];
  float4 v0 = *(const float4*)&covb[i8],      v1 = *(const float4*)&covb[i8 + 4];
  float covbt = cov[b * TT + t];
  float p1 = dot4(*(const float4*)&e[0], a0) + dot4(*(const float4*)&e[4], a1)
           + dot4(s0, b0) + dot4(s1, b1)
           + dot4(v0, c0) + dot4(v1, c1);
  float p2 = dot4(w0, c0) + dot4(w1, c1);
  float d = wredsum(p1 + covbt * p2);
  if (lane == 0) ts[b * TT + t] = tanhf(d + ab[0]);
}

// ---------------- attention softmax over T + new_coverage + scatter + loss ----------------
__global__ void attn_kernel(const float* __restrict__ ts, const float* __restrict__ cov,
                            const int* __restrict__ src,
                            float* __restrict__ wattn, float* __restrict__ dout,
                            float* __restrict__ outc) {
  int b = blockIdx.x, tid = threadIdx.x;
  int lane = tid & 63, wid = tid >> 6;
  __shared__ float sred[8];
  __shared__ float bval[2];
  float v = (tid < TT) ? ts[b * TT + tid] : -1e30f;
  float wm = wredmax(v);
  if (lane == 0) sred[wid] = wm;
  __syncthreads();
  if (wid == 0) {
    float r = (lane < 8) ? sred[lane] : -1e30f;
    r = wredmax(r);
    if (lane == 0) bval[0] = r;
  }
  __syncthreads();
  float m = bval[0];
  float e = (tid < TT) ? expf(v - m) : 0.f;
  float wsm = wredsum(e);
  __syncthreads();
  if (lane == 0) sred[wid] = wsm;
  __syncthreads();
  if (wid == 0) {
    float r = (lane < 8) ? sred[lane] : 0.f;
    r = wredsum(r);
    if (lane == 0) bval[1] = r;
  }
  __syncthreads();
  float denom = bval[1];
  float a = e / denom;
  float lp = 0.f;
  if (tid < TT) {
    wattn[b * TT + tid] = a;
    dout[OFF_ATTN + b * TT + tid] = a;
    float c = cov[b * TT + tid];
    dout[OFF_NEWCOV + b * TT + tid] = c + a;
    lp = fminf(a, c);
    atomicAdd(&outc[(size_t)b * VV + src[b * TT + tid]], a);
  }
  float wl = wredsum(lp);
  __syncthreads();
  if (lane == 0) sred[wid] = wl;
  __syncthreads();
  if (wid == 0) {
    float r = (lane < 8) ? sred[lane] : 0.f;
    r = wredsum(r);
    if (lane == 0) atomicAdd(&dout[OFF_LOSS], r);
  }
}

// ---------------- context + p_gen fused: one block per b ----------------
__global__ void ctxpgen_kernel(const float* __restrict__ enc, const float* __restrict__ attn,
                               const float* __restrict__ s, const float* __restrict__ embt,
                               const int* __restrict__ ids, const float* __restrict__ gW,
                               const float* __restrict__ gb,
                               float* __restrict__ ctx, float* __restrict__ pgen) {
  int b = blockIdx.x, tid = threadIdx.x;     // 512 threads
  int lane = tid & 63, wid = tid >> 6;
  __shared__ float as[TT];
  __shared__ float sred[8];
  if (tid < TT) as[tid] = attn[b * TT + tid];
  __syncthreads();
  const float* e = enc + (size_t)b * TT * HH + tid;
  float acc = 0.f;
#pragma unroll 8
  for (int t = 0; t < TT; t++) acc += as[t] * e[(size_t)t * HH];
  ctx[b * HH + tid] = acc;
  float part = acc * gW[tid] + s[b * HH + tid] * gW[HH + tid];
  if (tid < EE) part += embt[(size_t)ids[b] * EE + tid] * gW[2 * HH + tid];
  float w = wredsum(part);
  if (lane == 0) sred[wid] = w;
  __syncthreads();
  if (wid == 0) {
    float r = (lane < 8) ? sred[lane] : 0.f;
    r = wredsum(r);
    if (lane == 0) pgen[b] = sigmoidf(r + gb[0]);
  }
}

// ---------------- fc1: ni = tanh([s,ctx] @ W^T + b), output bf16 ----------------
__global__ void fc1_kernel(const float* __restrict__ s, const float* __restrict__ ctx,
                           const float* __restrict__ W, const float* __restrict__ bias,
                           short* __restrict__ nib) {
  int b = blockIdx.x >> 2;
  int k = (blockIdx.x & 3) * 256 + threadIdx.x;
  __shared__ float in[H4];
#pragma unroll
  for (int q = 0; q < 4; q++) {
    int i = q * 256 + threadIdx.x;
    in[i] = (i < HH) ? s[b * HH + i] : ctx[b * HH + i - HH];
  }
  __syncthreads();
  const float* w = W + (size_t)k * H4;
  float acc = 0.f;
  for (int i = 0; i < H4; i += 4)
    acc += dot4(*(const float4*)&w[i], *(const float4*)&in[i]);
  nib[(size_t)b * H4 + k] = bfh(tanhf(acc + bias[k]));
}

// ---------------- fc2 via MFMA bf16: logits[64][50000] = ni @ W^T + b ----------------
__global__ __launch_bounds__(256) void fc2_kernel(const short* __restrict__ nib,
                                                  const float* __restrict__ W,
                                                  const float* __restrict__ bias,
                                                  float* __restrict__ logits) {
  int nf = blockIdx.x * 4 + (threadIdx.x >> 6);
  if (nf >= VV / 16) return;
  int lane = threadIdx.x & 63;
  int r16 = lane & 15;
  int kg = lane >> 4;
  int v0 = nf * 16;

  f32x4 acc0 = {0.f,0.f,0.f,0.f}, acc1 = {0.f,0.f,0.f,0.f};
  f32x4 acc2 = {0.f,0.f,0.f,0.f}, acc3 = {0.f,0.f,0.f,0.f};

  const float* wp = W + (size_t)(v0 + r16) * H4 + kg * 8;
  const short* ap = nib + (size_t)r16 * H4 + kg * 8;

#pragma unroll 2
  for (int k0 = 0; k0 < H4; k0 += 32) {
    float4 w0 = *(const float4*)&wp[k0];
    float4 w1 = *(const float4*)&wp[k0 + 4];
    short8v bf;
    bf[0] = bfh(w0.x); bf[1] = bfh(w0.y); bf[2] = bfh(w0.z); bf[3] = bfh(w0.w);
    bf[4] = bfh(w1.x); bf[5] = bfh(w1.y); bf[6] = bfh(w1.z); bf[7] = bfh(w1.w);
    short8v a0 = *(const short8v*)&ap[k0];
    short8v a1 = *(const short8v*)&ap[16 * H4 + k0];
    short8v a2 = *(const short8v*)&ap[32 * H4 + k0];
    short8v a3 = *(const short8v*)&ap[48 * H4 + k0];
    acc0 = __builtin_amdgcn_mfma_f32_16x16x32_bf16(a0, bf, acc0, 0, 0, 0);
    acc1 = __builtin_amdgcn_mfma_f32_16x16x32_bf16(a1, bf, acc1, 0, 0, 0);
    acc2 = __builtin_amdgcn_mfma_f32_16x16x32_bf16(a2, bf, acc2, 0, 0, 0);
    acc3 = __builtin_amdgcn_mfma_f32_16x16x32_bf16(a3, bf, acc3, 0, 0, 0);
  }

  float bv = bias[v0 + r16];
  size_t col = (size_t)v0 + r16;
  int rbase = kg * 4;
#pragma unroll
  for (int r = 0; r < 4; r++) {
    logits[(size_t)(rbase + r) * VV + col]      = acc0[r] + bv;
    logits[(size_t)(16 + rbase + r) * VV + col] = acc1[r] + bv;
    logits[(size_t)(32 + rbase + r) * VV + col] = acc2[r] + bv;
    logits[(size_t)(48 + rbase + r) * VV + col] = acc3[r] + bv;
  }
}

// ---------------- per-row vocab softmax stats ----------------
__global__ void smax_kernel(const float* __restrict__ logits, float* __restrict__ rm,
                            float* __restrict__ rs) {
  int b = blockIdx.x, tid = threadIdx.x;
  int lane = tid & 63, wid = tid >> 6;
  __shared__ float sred[4];
  __shared__ float bval[2];
  const float4* row = (const float4*)(logits + (size_t)b * VV);
  float m = -1e30f;
  for (int i = tid; i < VV / 4; i += 256) {
    float4 l = row[i];
    m = fmaxf(m, fmaxf(fmaxf(l.x, l.y), fmaxf(l.z, l.w)));
  }
  m = wredmax(m);
  if (lane == 0) sred[wid] = m;
  __syncthreads();
  if (wid == 0) {
    float r = (lane < 4) ? sred[lane] : -1e30f;
    r = wredmax(r);
    if (lane == 0) bval[0] = r;
  }
  __syncthreads();
  float bm = bval[0];
  float sacc = 0.f;
  for (int i = tid; i < VV / 4; i += 256) {
    float4 l = row[i];
    sacc += expf(l.x - bm) + expf(l.y - bm) + expf(l.z - bm) + expf(l.w - bm);
  }
  sacc = wredsum(sacc);
  __syncthreads();
  if (lane == 0) sred[wid] = sacc;
  __syncthreads();
  if (wid == 0) {
    float r = (lane < 4) ? sred[lane] : 0.f;
    r = wredsum(r);
    if (lane == 0) { rm[b] = bm; rs[b] = r; }
  }
}

// ---------------- final mix: out = Pvocab*p_gen + copy*(1-p_gen) ----------------
__global__ void final_kernel(const float* __restrict__ logits, const float* __restrict__ rm,
                             const float* __restrict__ rs, const float* __restrict__ pgen,
                             const float* __restrict__ copy, float* __restrict__ out) {
  int i = blockIdx.x * 256 + threadIdx.x;     // over 800000 float4s
  int b = (i * 4) / VV;
  float p = pgen[b], m = rm[b], s = rs[b];
  float4 l = ((const float4*)logits)[i];
  float4 c = ((const float4*)copy)[i];
  float q = 1.f - p;
  float4 o;
  o.x = expf(l.x - m) / s * p + c.x * q;
  o.y = expf(l.y - m) / s * p + c.y * q;
  o.z = expf(l.z - m) / s * p + c.z * q;
  o.w = expf(l.w - m) / s * p + c.w * q;
  ((float4*)out)[i] = o;
}

extern "C" void kernel_launch(void* const* d_in, const int* in_sizes, int n_in,
                              void* d_out, int out_size, void* d_ws, size_t ws_size,
                              hipStream_t stream) {
  const int*   ids  = (const int*)d_in[0];
  const float* preh = (const float*)d_in[1];
  const float* enc  = (const float*)d_in[2];
  const int*   src  = (const int*)d_in[3];
  const float* cov  = (const float*)d_in[4];
  const float* embt = (const float*)d_in[5];
  const float* Wih0 = (const float*)d_in[6];
  const float* Whh0 = (const float*)d_in[7];
  const float* bih0 = (const float*)d_in[8];
  const float* bhh0 = (const float*)d_in[9];
  const float* Wih1 = (const float*)d_in[10];
  const float* Whh1 = (const float*)d_in[11];
  const float* bih1 = (const float*)d_in[12];
  const float* bhh1 = (const float*)d_in[13];
  const float* aW   = (const float*)d_in[14];
  const float* ab   = (const float*)d_in[15];
  const float* covW = (const float*)d_in[16];
  const float* covb = (const float*)d_in[17];
  const float* f1W  = (const float*)d_in[18];
  const float* f1b  = (const float*)d_in[19];
  const float* f2W  = (const float*)d_in[20];
  const float* f2b  = (const float*)d_in[21];
  const float* gW   = (const float*)d_in[22];
  const float* gb   = (const float*)d_in[23];
  float* out = (float*)d_out;
  float* ws  = (float*)d_ws;

  zero_kernel<<<3125, 256, 0, stream>>>(out + OFF_COPY, out + OFF_LOSS);
  prep_kernel<<<288, 256, 0, stream>>>(embt, ids, preh,
                                       (short*)(ws + WS_AX0), (short*)(ws + WS_AH0),
                                       (short*)(ws + WS_AH1));
  gru_mfma_kernel<EE><<<32, 192, 0, stream>>>(
      (const short*)(ws + WS_AX0), (const short*)(ws + WS_AH0),
      Wih0, Whh0, bih0, bhh0, preh,
      out + OFF_CURHID, out + OFF_CURHID, (short*)(ws + WS_AX1));
  gru_mfma_kernel<HH><<<32, 192, 0, stream>>>(
      (const short*)(ws + WS_AX1), (const short*)(ws + WS_AH1),
      Wih1, Whh1, bih1, bhh1, preh + BB * HH,
      ws + WS_S, out + OFF_CURHID + BB * HH, (short*)(ws + WS_SB));
  scores_kernel<<<dim3(100, 64), 256, 0, stream>>>(enc, cov, aW, ab, covW, covb,
                                                   ws + WS_S, ws + WS_TS);
  attn_kernel<<<64, 512, 0, stream>>>(ws + WS_TS, cov, src, ws + WS_ATTN, out,
                                      out + OFF_COPY);
  ctxpgen_kernel<<<64, 512, 0, stream>>>(enc, ws + WS_ATTN, ws + WS_S, embt, ids, gW, gb,
                                         ws + WS_CTX, ws + WS_PGEN);
  fc1_kernel<<<256, 256, 0, stream>>>(ws + WS_S, ws + WS_CTX, f1W, f1b,
                                      (short*)(ws + WS_NI));
  fc2_kernel<<<782, 256, 0, stream>>>((const short*)(ws + WS_NI), f2W, f2b,
                                      ws + WS_LOGITS);
  smax_kernel<<<64, 256, 0, stream>>>(ws + WS_LOGITS, ws + WS_RM, ws + WS_RS);
  final_kernel<<<3125, 256, 0, stream>>>(ws + WS_LOGITS, ws + WS_RM, ws + WS_RS,
                                         ws + WS_PGEN, out + OFF_COPY, out);
}

// Round 4
// 199.960 us; speedup vs baseline: 2.8375x; 1.3319x over previous
//
#include <hip/hip_runtime.h>
#include <hip/hip_bf16.h>
#include <cstddef>

#define BB 64
#define TT 400
#define EE 128
#define HH 512
#define H4 1024
#define VV 50000

// ---- d_out layout (floats), reference return order ----
#define OFF_OUT     0
#define OFF_CURHID  (BB*VV)                    // 3,200,000
#define OFF_ATTN    (OFF_CURHID + 2*BB*HH)     // 3,265,536
#define OFF_COPY    (OFF_ATTN + BB*TT)         // 3,291,136
#define OFF_NEWCOV  (OFF_COPY + BB*VV)         // 6,491,136
#define OFF_LOSS    (OFF_NEWCOV + BB*TT)       // 6,516,736

// ---- workspace layout (floats; bf16 buffers noted) ----
#define WS_S      0                            // f32 s 64x512
#define WS_TS     (WS_S + BB*HH)
#define WS_ATTN   (WS_TS + BB*TT)
#define WS_NIB    (WS_ATTN + BB*TT)            // bf16 ni 64x1024 (16384 floats)
#define WS_A1     (WS_NIB + BB*H4/2)           // bf16 [s|ctx] 64x1024
#define WS_AX0    (WS_A1 + BB*H4/2)            // bf16 emb 64x128
#define WS_AH0    (WS_AX0 + BB*EE/2)           // bf16 h_prev0 64x512
#define WS_AH1    (WS_AH0 + BB*HH/2)           // bf16 h_prev1 64x512
#define WS_AX1    (WS_AH1 + BB*HH/2)           // bf16 h0 64x512
#define WS_PGEN   (WS_AX1 + BB*HH/2)
#define WS_RM     (WS_PGEN + 64)
#define WS_RS     (WS_RM + 64)
#define WS_LOGITS (WS_RS + 64)                 // f32 64x50000

typedef __attribute__((ext_vector_type(8))) short short8v;
typedef __attribute__((ext_vector_type(4))) float f32x4;

__device__ __forceinline__ float wredsum(float v) {
#pragma unroll
  for (int o = 32; o > 0; o >>= 1) v += __shfl_down(v, o, 64);
  return v;
}
__device__ __forceinline__ float wredmax(float v) {
#pragma unroll
  for (int o = 32; o > 0; o >>= 1) v = fmaxf(v, __shfl_down(v, o, 64));
  return v;
}
__device__ __forceinline__ float dot4(float4 a, float4 b) {
  return a.x*b.x + a.y*b.y + a.z*b.z + a.w*b.w;
}
__device__ __forceinline__ float sigmoidf(float x) { return 1.f / (1.f + expf(-x)); }
__device__ __forceinline__ short bfh(float f) {
  union { __hip_bfloat16 h; short s; } u; u.h = __float2bfloat16(f); return u.s;
}

// ---------------- zero copy_prob region + loss slot ----------------
__global__ void zero_kernel(float* __restrict__ p, float* __restrict__ loss) {
  int i = blockIdx.x * 256 + threadIdx.x;   // 800000 float4s
  ((float4*)p)[i] = make_float4(0.f, 0.f, 0.f, 0.f);
  if (i == 0) loss[0] = 0.f;
}

// ---------------- prep: bf16 conversions for GRU A-operands ----------------
__global__ void prep_kernel(const float* __restrict__ embt, const int* __restrict__ ids,
                            const float* __restrict__ preh,
                            short* __restrict__ ax0, short* __restrict__ ah0,
                            short* __restrict__ ah1) {
  int tid = blockIdx.x * 256 + threadIdx.x;   // 73728 total
  if (tid < BB * EE) {
    int b = tid >> 7, k = tid & 127;
    ax0[tid] = bfh(embt[(size_t)ids[b] * EE + k]);
  } else {
    int i = tid - BB * EE;                    // 0..65535
    if (i < BB * HH) ah0[i] = bfh(preh[i]);
    else ah1[i - BB * HH] = bfh(preh[i]);
  }
}

// ---------------- GRU layer via MFMA ----------------
// 128 blocks = 32 col-frags x 4 batch-groups; 6 waves = {r,z,n} x {ih,hh}.
// Each wave computes one 16x16 partial (batch-group x gate-cols), LDS
// exchange, wave 0 applies gating. ih/hh kept separate (n-gate needs r*gh_n).
template<int KX>
__global__ __launch_bounds__(384) void gru_mfma_kernel(
    const short* __restrict__ Ax, const short* __restrict__ Ah,
    const float* __restrict__ W_ih, const float* __restrict__ W_hh,
    const float* __restrict__ b_ih, const float* __restrict__ b_hh,
    const float* __restrict__ hprev,
    float* __restrict__ hout_f, float* __restrict__ hout_o,
    short* __restrict__ hout_b, int bstride) {
  __shared__ float P[2][3][16][16];
  const int w = threadIdx.x >> 6;             // 0..5
  const int lane = threadIdx.x & 63;
  const int r16 = lane & 15, kg = lane >> 4;
  const int j0 = (blockIdx.x & 31) * 16;      // gate-col fragment
  const int bg = blockIdx.x >> 5;             // batch group (16 rows)
  const int part = (w >= 3) ? 1 : 0;          // 0 = ih, 1 = hh
  const int g = w - part * 3;                 // gate r/z/n
  const int K = part ? HH : KX;
  const float* Wm = part ? W_hh : W_ih;
  const short* Am = part ? Ah : Ax;

  f32x4 acc = {0.f, 0.f, 0.f, 0.f};
  const float* wp = Wm + (size_t)(g * HH + j0 + r16) * K + kg * 8;
  const short* ap = Am + (size_t)(bg * 16 + r16) * K + kg * 8;
#pragma unroll 4
  for (int k0 = 0; k0 < K; k0 += 32) {
    float4 w0 = *(const float4*)(wp + k0);
    float4 w1 = *(const float4*)(wp + k0 + 4);
    short8v a = *(const short8v*)(ap + k0);
    short8v bf;
    bf[0] = bfh(w0.x); bf[1] = bfh(w0.y); bf[2] = bfh(w0.z); bf[3] = bfh(w0.w);
    bf[4] = bfh(w1.x); bf[5] = bfh(w1.y); bf[6] = bfh(w1.z); bf[7] = bfh(w1.w);
    acc = __builtin_amdgcn_mfma_f32_16x16x32_bf16(a, bf, acc, 0, 0, 0);
  }
#pragma unroll
  for (int r = 0; r < 4; r++) P[part][g][kg * 4 + r][r16] = acc[r];
  __syncthreads();
  if (w == 0) {
    int col = j0 + r16;
    float bir = b_ih[col] + b_hh[col];
    float biz = b_ih[HH + col] + b_hh[HH + col];
    float bin = b_ih[2 * HH + col], bhn = b_hh[2 * HH + col];
#pragma unroll
    for (int r = 0; r < 4; r++) {
      int m = kg * 4 + r;
      int row = bg * 16 + m;
      float rv = sigmoidf(P[0][0][m][r16] + P[1][0][m][r16] + bir);
      float zv = sigmoidf(P[0][1][m][r16] + P[1][1][m][r16] + biz);
      float nv = tanhf(P[0][2][m][r16] + bin + rv * (P[1][2][m][r16] + bhn));
      float h = (1.f - zv) * nv + zv * hprev[(size_t)row * HH + col];
      hout_f[(size_t)row * HH + col] = h;
      hout_o[(size_t)row * HH + col] = h;
      hout_b[(size_t)row * bstride + col] = bfh(h);
    }
  }
}

// ---------------- tanh(scores): one wave per (b,t); sdot/cc fused in ----------------
__global__ void scores_kernel(const float* __restrict__ enc, const float* __restrict__ cov,
                              const float* __restrict__ aW, const float* __restrict__ ab,
                              const float* __restrict__ covW, const float* __restrict__ covb,
                              const float* __restrict__ s, float* __restrict__ ts) {
  int b = blockIdx.y;
  int wid = threadIdx.x >> 6, lane = threadIdx.x & 63;
  int t = blockIdx.x * 4 + wid;
  int i8 = lane * 8;
  const float* e = enc + ((size_t)b * TT + t) * HH + i8;
  float4 a0 = *(const float4*)&aW[i8],        a1 = *(const float4*)&aW[i8 + 4];
  float4 b0 = *(const float4*)&aW[HH + i8],   b1 = *(const float4*)&aW[HH + i8 + 4];
  float4 c0 = *(const float4*)&aW[2*HH + i8], c1 = *(const float4*)&aW[2*HH + i8 + 4];
  float4 s0 = *(const float4*)&s[(size_t)b * HH + i8], s1 = *(const float4*)&s[(size_t)b * HH + i8 + 4];
  float4 w0 = *(const float4*)&covW[i8],      w1 = *(const float4*)&covW[i8 + 4];
  float4 v0 = *(const float4*)&covb[i8],      v1 = *(const float4*)&covb[i8 + 4];
  float covbt = cov[b * TT + t];
  float p1 = dot4(*(const float4*)&e[0], a0) + dot4(*(const float4*)&e[4], a1)
           + dot4(s0, b0) + dot4(s1, b1)
           + dot4(v0, c0) + dot4(v1, c1);
  float p2 = dot4(w0, c0) + dot4(w1, c1);
  float d = wredsum(p1 + covbt * p2);
  if (lane == 0) ts[b * TT + t] = tanhf(d + ab[0]);
}

// ---------------- attention softmax over T + new_coverage + scatter + loss ----------------
__global__ void attn_kernel(const float* __restrict__ ts, const float* __restrict__ cov,
                            const int* __restrict__ src,
                            float* __restrict__ wattn, float* __restrict__ dout,
                            float* __restrict__ outc) {
  int b = blockIdx.x, tid = threadIdx.x;
  int lane = tid & 63, wid = tid >> 6;
  __shared__ float sred[8];
  __shared__ float bval[2];
  float v = (tid < TT) ? ts[b * TT + tid] : -1e30f;
  float wm = wredmax(v);
  if (lane == 0) sred[wid] = wm;
  __syncthreads();
  if (wid == 0) {
    float r = (lane < 8) ? sred[lane] : -1e30f;
    r = wredmax(r);
    if (lane == 0) bval[0] = r;
  }
  __syncthreads();
  float m = bval[0];
  float e = (tid < TT) ? expf(v - m) : 0.f;
  float wsm = wredsum(e);
  __syncthreads();
  if (lane == 0) sred[wid] = wsm;
  __syncthreads();
  if (wid == 0) {
    float r = (lane < 8) ? sred[lane] : 0.f;
    r = wredsum(r);
    if (lane == 0) bval[1] = r;
  }
  __syncthreads();
  float denom = bval[1];
  float a = e / denom;
  float lp = 0.f;
  if (tid < TT) {
    wattn[b * TT + tid] = a;
    dout[OFF_ATTN + b * TT + tid] = a;
    float c = cov[b * TT + tid];
    dout[OFF_NEWCOV + b * TT + tid] = c + a;
    lp = fminf(a, c);
    atomicAdd(&outc[(size_t)b * VV + src[b * TT + tid]], a);
  }
  float wl = wredsum(lp);
  __syncthreads();
  if (lane == 0) sred[wid] = wl;
  __syncthreads();
  if (wid == 0) {
    float r = (lane < 8) ? sred[lane] : 0.f;
    r = wredsum(r);
    if (lane == 0) atomicAdd(&dout[OFF_LOSS], r);
  }
}

// ---------------- context + p_gen fused: one block per b; ctx out as bf16 into A1 ----
__global__ void ctxpgen_kernel(const float* __restrict__ enc, const float* __restrict__ attn,
                               const float* __restrict__ s, const float* __restrict__ embt,
                               const int* __restrict__ ids, const float* __restrict__ gW,
                               const float* __restrict__ gb,
                               short* __restrict__ a1, float* __restrict__ pgen) {
  int b = blockIdx.x, tid = threadIdx.x;     // 512 threads
  int lane = tid & 63, wid = tid >> 6;
  __shared__ float as[TT];
  __shared__ float sred[8];
  if (tid < TT) as[tid] = attn[b * TT + tid];
  __syncthreads();
  const float* e = enc + (size_t)b * TT * HH + tid;
  float acc = 0.f;
#pragma unroll 8
  for (int t = 0; t < TT; t++) acc += as[t] * e[(size_t)t * HH];
  a1[(size_t)b * H4 + HH + tid] = bfh(acc);
  float part = acc * gW[tid] + s[b * HH + tid] * gW[HH + tid];
  if (tid < EE) part += embt[(size_t)ids[b] * EE + tid] * gW[2 * HH + tid];
  float w = wredsum(part);
  if (lane == 0) sred[wid] = w;
  __syncthreads();
  if (wid == 0) {
    float r = (lane < 8) ? sred[lane] : 0.f;
    r = wredsum(r);
    if (lane == 0) pgen[b] = sigmoidf(r + gb[0]);
  }
}

// ---------------- fc1 via MFMA, K-split 4: ni = tanh(A1 @ W^T + b) -> bf16 ----------------
__global__ __launch_bounds__(256) void fc1_kernel(const short* __restrict__ a1,
                                                  const float* __restrict__ W,
                                                  const float* __restrict__ bias,
                                                  short* __restrict__ nib) {
  __shared__ float part[4096];
  const int w = threadIdx.x >> 6;
  const int lane = threadIdx.x & 63;
  const int r16 = lane & 15, kg = lane >> 4;
  const int v0 = blockIdx.x * 16;
  const int kb = w * 256;

  f32x4 acc0 = {0.f,0.f,0.f,0.f}, acc1 = {0.f,0.f,0.f,0.f};
  f32x4 acc2 = {0.f,0.f,0.f,0.f}, acc3 = {0.f,0.f,0.f,0.f};
  const float* wp = W + (size_t)(v0 + r16) * H4 + kb + kg * 8;
  const short* ap = a1 + (size_t)r16 * H4 + kb + kg * 8;
#pragma unroll 4
  for (int k0 = 0; k0 < 256; k0 += 32) {
    float4 w0 = *(const float4*)(wp + k0);
    float4 w1 = *(const float4*)(wp + k0 + 4);
    short8v a0 = *(const short8v*)(ap + k0);
    short8v a1v = *(const short8v*)(ap + 16 * H4 + k0);
    short8v a2 = *(const short8v*)(ap + 32 * H4 + k0);
    short8v a3 = *(const short8v*)(ap + 48 * H4 + k0);
    short8v bf;
    bf[0] = bfh(w0.x); bf[1] = bfh(w0.y); bf[2] = bfh(w0.z); bf[3] = bfh(w0.w);
    bf[4] = bfh(w1.x); bf[5] = bfh(w1.y); bf[6] = bfh(w1.z); bf[7] = bfh(w1.w);
    acc0 = __builtin_amdgcn_mfma_f32_16x16x32_bf16(a0, bf, acc0, 0, 0, 0);
    acc1 = __builtin_amdgcn_mfma_f32_16x16x32_bf16(a1v, bf, acc1, 0, 0, 0);
    acc2 = __builtin_amdgcn_mfma_f32_16x16x32_bf16(a2, bf, acc2, 0, 0, 0);
    acc3 = __builtin_amdgcn_mfma_f32_16x16x32_bf16(a3, bf, acc3, 0, 0, 0);
  }
  float* pb = part + w * 1024;
#pragma unroll
  for (int r = 0; r < 4; r++) {
    pb[(kg * 4 + r) * 16 + r16]      = acc0[r];
    pb[(16 + kg * 4 + r) * 16 + r16] = acc1[r];
    pb[(32 + kg * 4 + r) * 16 + r16] = acc2[r];
    pb[(48 + kg * 4 + r) * 16 + r16] = acc3[r];
  }
  __syncthreads();
  int idx = threadIdx.x * 4;
  int m = idx >> 4, c0 = idx & 15;
  f32x4 s0 = *(const f32x4*)(part + idx);
  f32x4 s1 = *(const f32x4*)(part + 1024 + idx);
  f32x4 s2 = *(const f32x4*)(part + 2048 + idx);
  f32x4 s3 = *(const f32x4*)(part + 3072 + idx);
  f32x4 bv = *(const f32x4*)(bias + v0 + c0);
  f32x4 o = s0 + s1 + s2 + s3 + bv;
#pragma unroll
  for (int j = 0; j < 4; j++)
    nib[(size_t)m * H4 + v0 + c0 + j] = bfh(tanhf(o[j]));
}

// ---------------- fc2 via MFMA, K-split 4: logits = ni @ W^T + b ----------------
__global__ __launch_bounds__(256, 4) void fc2_kernel(const short* __restrict__ nib,
                                                     const float* __restrict__ W,
                                                     const float* __restrict__ bias,
                                                     float* __restrict__ logits) {
  __shared__ float part[4096];
  const int w = threadIdx.x >> 6;
  const int lane = threadIdx.x & 63;
  const int r16 = lane & 15, kg = lane >> 4;
  const int v0 = blockIdx.x * 16;
  const int kb = w * 256;

  f32x4 acc0 = {0.f,0.f,0.f,0.f}, acc1 = {0.f,0.f,0.f,0.f};
  f32x4 acc2 = {0.f,0.f,0.f,0.f}, acc3 = {0.f,0.f,0.f,0.f};
  const float* wp = W + (size_t)(v0 + r16) * H4 + kb + kg * 8;
  const short* ap = nib + (size_t)r16 * H4 + kb + kg * 8;
#pragma unroll 4
  for (int k0 = 0; k0 < 256; k0 += 32) {
    float4 w0 = *(const float4*)(wp + k0);
    float4 w1 = *(const float4*)(wp + k0 + 4);
    short8v a0 = *(const short8v*)(ap + k0);
    short8v a1 = *(const short8v*)(ap + 16 * H4 + k0);
    short8v a2 = *(const short8v*)(ap + 32 * H4 + k0);
    short8v a3 = *(const short8v*)(ap + 48 * H4 + k0);
    short8v bf;
    bf[0] = bfh(w0.x); bf[1] = bfh(w0.y); bf[2] = bfh(w0.z); bf[3] = bfh(w0.w);
    bf[4] = bfh(w1.x); bf[5] = bfh(w1.y); bf[6] = bfh(w1.z); bf[7] = bfh(w1.w);
    acc0 = __builtin_amdgcn_mfma_f32_16x16x32_bf16(a0, bf, acc0, 0, 0, 0);
    acc1 = __builtin_amdgcn_mfma_f32_16x16x32_bf16(a1, bf, acc1, 0, 0, 0);
    acc2 = __builtin_amdgcn_mfma_f32_16x16x32_bf16(a2, bf, acc2, 0, 0, 0);
    acc3 = __builtin_amdgcn_mfma_f32_16x16x32_bf16(a3, bf, acc3, 0, 0, 0);
  }
  float* pb = part + w * 1024;
#pragma unroll
  for (int r = 0; r < 4; r++) {
    pb[(kg * 4 + r) * 16 + r16]      = acc0[r];
    pb[(16 + kg * 4 + r) * 16 + r16] = acc1[r];
    pb[(32 + kg * 4 + r) * 16 + r16] = acc2[r];
    pb[(48 + kg * 4 + r) * 16 + r16] = acc3[r];
  }
  __syncthreads();
  int idx = threadIdx.x * 4;
  int m = idx >> 4, c0 = idx & 15;
  f32x4 s0 = *(const f32x4*)(part + idx);
  f32x4 s1 = *(const f32x4*)(part + 1024 + idx);
  f32x4 s2 = *(const f32x4*)(part + 2048 + idx);
  f32x4 s3 = *(const f32x4*)(part + 3072 + idx);
  f32x4 bv = *(const f32x4*)(bias + v0 + c0);
  f32x4 o = s0 + s1 + s2 + s3 + bv;
  *(f32x4*)(logits + (size_t)m * VV + v0 + c0) = o;
}

// ---------------- per-row vocab softmax stats ----------------
__global__ void smax_kernel(const float* __restrict__ logits, float* __restrict__ rm,
                            float* __restrict__ rs) {
  int b = blockIdx.x, tid = threadIdx.x;
  int lane = tid & 63, wid = tid >> 6;
  __shared__ float sred[4];
  __shared__ float bval[2];
  const float4* row = (const float4*)(logits + (size_t)b * VV);
  float m = -1e30f;
  for (int i = tid; i < VV / 4; i += 256) {
    float4 l = row[i];
    m = fmaxf(m, fmaxf(fmaxf(l.x, l.y), fmaxf(l.z, l.w)));
  }
  m = wredmax(m);
  if (lane == 0) sred[wid] = m;
  __syncthreads();
  if (wid == 0) {
    float r = (lane < 4) ? sred[lane] : -1e30f;
    r = wredmax(r);
    if (lane == 0) bval[0] = r;
  }
  __syncthreads();
  float bm = bval[0];
  float sacc = 0.f;
  for (int i = tid; i < VV / 4; i += 256) {
    float4 l = row[i];
    sacc += expf(l.x - bm) + expf(l.y - bm) + expf(l.z - bm) + expf(l.w - bm);
  }
  sacc = wredsum(sacc);
  __syncthreads();
  if (lane == 0) sred[wid] = sacc;
  __syncthreads();
  if (wid == 0) {
    float r = (lane < 4) ? sred[lane] : 0.f;
    r = wredsum(r);
    if (lane == 0) { rm[b] = bm; rs[b] = r; }
  }
}

// ---------------- final mix: out = Pvocab*p_gen + copy*(1-p_gen) ----------------
__global__ void final_kernel(const float* __restrict__ logits, const float* __restrict__ rm,
                             const float* __restrict__ rs, const float* __restrict__ pgen,
                             const float* __restrict__ copy, float* __restrict__ out) {
  int i = blockIdx.x * 256 + threadIdx.x;     // over 800000 float4s
  int b = (i * 4) / VV;
  float p = pgen[b], m = rm[b], s = rs[b];
  float4 l = ((const float4*)logits)[i];
  float4 c = ((const float4*)copy)[i];
  float q = 1.f - p;
  float4 o;
  o.x = expf(l.x - m) / s * p + c.x * q;
  o.y = expf(l.y - m) / s * p + c.y * q;
  o.z = expf(l.z - m) / s * p + c.z * q;
  o.w = expf(l.w - m) / s * p + c.w * q;
  ((float4*)out)[i] = o;
}

extern "C" void kernel_launch(void* const* d_in, const int* in_sizes, int n_in,
                              void* d_out, int out_size, void* d_ws, size_t ws_size,
                              hipStream_t stream) {
  const int*   ids  = (const int*)d_in[0];
  const float* preh = (const float*)d_in[1];
  const float* enc  = (const float*)d_in[2];
  const int*   src  = (const int*)d_in[3];
  const float* cov  = (const float*)d_in[4];
  const float* embt = (const float*)d_in[5];
  const float* Wih0 = (const float*)d_in[6];
  const float* Whh0 = (const float*)d_in[7];
  const float* bih0 = (const float*)d_in[8];
  const float* bhh0 = (const float*)d_in[9];
  const float* Wih1 = (const float*)d_in[10];
  const float* Whh1 = (const float*)d_in[11];
  const float* bih1 = (const float*)d_in[12];
  const float* bhh1 = (const float*)d_in[13];
  const float* aW   = (const float*)d_in[14];
  const float* ab   = (const float*)d_in[15];
  const float* covW = (const float*)d_in[16];
  const float* covb = (const float*)d_in[17];
  const float* f1W  = (const float*)d_in[18];
  const float* f1b  = (const float*)d_in[19];
  const float* f2W  = (const float*)d_in[20];
  const float* f2b  = (const float*)d_in[21];
  const float* gW   = (const float*)d_in[22];
  const float* gb   = (const float*)d_in[23];
  float* out = (float*)d_out;
  float* ws  = (float*)d_ws;

  zero_kernel<<<3125, 256, 0, stream>>>(out + OFF_COPY, out + OFF_LOSS);
  prep_kernel<<<288, 256, 0, stream>>>(embt, ids, preh,
                                       (short*)(ws + WS_AX0), (short*)(ws + WS_AH0),
                                       (short*)(ws + WS_AH1));
  gru_mfma_kernel<EE><<<128, 384, 0, stream>>>(
      (const short*)(ws + WS_AX0), (const short*)(ws + WS_AH0),
      Wih0, Whh0, bih0, bhh0, preh,
      out + OFF_CURHID, out + OFF_CURHID, (short*)(ws + WS_AX1), HH);
  gru_mfma_kernel<HH><<<128, 384, 0, stream>>>(
      (const short*)(ws + WS_AX1), (const short*)(ws + WS_AH1),
      Wih1, Whh1, bih1, bhh1, preh + BB * HH,
      ws + WS_S, out + OFF_CURHID + BB * HH, (short*)(ws + WS_A1), H4);
  scores_kernel<<<dim3(100, 64), 256, 0, stream>>>(enc, cov, aW, ab, covW, covb,
                                                   ws + WS_S, ws + WS_TS);
  attn_kernel<<<64, 512, 0, stream>>>(ws + WS_TS, cov, src, ws + WS_ATTN, out,
                                      out + OFF_COPY);
  ctxpgen_kernel<<<64, 512, 0, stream>>>(enc, ws + WS_ATTN, ws + WS_S, embt, ids, gW, gb,
                                         (short*)(ws + WS_A1), ws + WS_PGEN);
  fc1_kernel<<<64, 256, 0, stream>>>((const short*)(ws + WS_A1), f1W, f1b,
                                     (short*)(ws + WS_NIB));
  fc2_kernel<<<3125, 256, 0, stream>>>((const short*)(ws + WS_NIB), f2W, f2b,
                                       ws + WS_LOGITS);
  smax_kernel<<<64, 256, 0, stream>>>(ws + WS_LOGITS, ws + WS_RM, ws + WS_RS);
  final_kernel<<<3125, 256, 0, stream>>>(ws + WS_LOGITS, ws + WS_RM, ws + WS_RS,
                                         ws + WS_PGEN, out + OFF_COPY, out);
}

// Round 5
// 188.464 us; speedup vs baseline: 3.0106x; 1.0610x over previous
//
#include <hip/hip_runtime.h>
#include <hip/hip_bf16.h>
#include <cstddef>

#define BB 64
#define TT 400
#define EE 128
#define HH 512
#define H4 1024
#define VV 50000
#define NCH 8                                  // ctx T-chunks

// ---- d_out layout (floats), reference return order ----
#define OFF_OUT     0
#define OFF_CURHID  (BB*VV)                    // 3,200,000
#define OFF_ATTN    (OFF_CURHID + 2*BB*HH)     // 3,265,536
#define OFF_COPY    (OFF_ATTN + BB*TT)         // 3,291,136
#define OFF_NEWCOV  (OFF_COPY + BB*VV)         // 6,491,136
#define OFF_LOSS    (OFF_NEWCOV + BB*TT)       // 6,516,736

// ---- workspace layout (floats; bf16 buffers noted) ----
#define WS_S      0                            // f32 s 64x512
#define WS_TS     (WS_S + BB*HH)
#define WS_ATTN   (WS_TS + BB*TT)
#define WS_NIB    (WS_ATTN + BB*TT)            // bf16 ni 64x1024
#define WS_A1     (WS_NIB + BB*H4/2)           // bf16 [s|ctx] 64x1024
#define WS_AX0    (WS_A1 + BB*H4/2)            // bf16 emb 64x128
#define WS_AH0    (WS_AX0 + BB*EE/2)           // bf16 h_prev0 64x512
#define WS_AH1    (WS_AH0 + BB*HH/2)           // bf16 h_prev1 64x512
#define WS_AX1    (WS_AH1 + BB*HH/2)           // bf16 h0 64x512
#define WS_PGEN   (WS_AX1 + BB*HH/2)
#define WS_RM     (WS_PGEN + 64)
#define WS_RS     (WS_RM + 64)
#define WS_CTXP   (WS_RS + 64)                 // f32 partial ctx 64x8x512 (1 MB)
#define WS_LOGITS (WS_CTXP + BB*NCH*HH)        // f32 64x50000

typedef __attribute__((ext_vector_type(8))) short short8v;
typedef __attribute__((ext_vector_type(4))) float f32x4;

__device__ __forceinline__ float wredsum(float v) {
#pragma unroll
  for (int o = 32; o > 0; o >>= 1) v += __shfl_down(v, o, 64);
  return v;
}
__device__ __forceinline__ float wredmax(float v) {
#pragma unroll
  for (int o = 32; o > 0; o >>= 1) v = fmaxf(v, __shfl_down(v, o, 64));
  return v;
}
__device__ __forceinline__ float dot4(float4 a, float4 b) {
  return a.x*b.x + a.y*b.y + a.z*b.z + a.w*b.w;
}
__device__ __forceinline__ float sigmoidf(float x) { return 1.f / (1.f + expf(-x)); }
__device__ __forceinline__ short bfh(float f) {
  union { __hip_bfloat16 h; short s; } u; u.h = __float2bfloat16(f); return u.s;
}

// ---------------- zero copy_prob + loss, and bf16 prep for GRU A-operands ----------------
__global__ void zero_prep_kernel(float* __restrict__ p, float* __restrict__ loss,
                                 const float* __restrict__ embt, const int* __restrict__ ids,
                                 const float* __restrict__ preh,
                                 short* __restrict__ ax0, short* __restrict__ ah0,
                                 short* __restrict__ ah1) {
  int i = blockIdx.x * 256 + threadIdx.x;   // 800000 float4s
  ((float4*)p)[i] = make_float4(0.f, 0.f, 0.f, 0.f);
  if (i == 0) loss[0] = 0.f;
  if (i < BB * EE) {
    int b = i >> 7, k = i & 127;
    ax0[i] = bfh(embt[(size_t)ids[b] * EE + k]);
  } else if (i < BB * EE + 2 * BB * HH) {
    int j = i - BB * EE;
    if (j < BB * HH) ah0[j] = bfh(preh[j]);
    else ah1[j - BB * HH] = bfh(preh[j]);
  }
}

// ---------------- GRU layer via MFMA ----------------
// 128 blocks = 32 col-frags x 4 batch-groups; 6 waves = {r,z,n} x {ih,hh}.
template<int KX>
__global__ __launch_bounds__(384) void gru_mfma_kernel(
    const short* __restrict__ Ax, const short* __restrict__ Ah,
    const float* __restrict__ W_ih, const float* __restrict__ W_hh,
    const float* __restrict__ b_ih, const float* __restrict__ b_hh,
    const float* __restrict__ hprev,
    float* __restrict__ hout_f, float* __restrict__ hout_o,
    short* __restrict__ hout_b, int bstride) {
  __shared__ float P[2][3][16][16];
  const int w = threadIdx.x >> 6;             // 0..5
  const int lane = threadIdx.x & 63;
  const int r16 = lane & 15, kg = lane >> 4;
  const int j0 = (blockIdx.x & 31) * 16;      // gate-col fragment
  const int bg = blockIdx.x >> 5;             // batch group (16 rows)
  const int part = (w >= 3) ? 1 : 0;          // 0 = ih, 1 = hh
  const int g = w - part * 3;                 // gate r/z/n
  const int K = part ? HH : KX;
  const float* Wm = part ? W_hh : W_ih;
  const short* Am = part ? Ah : Ax;

  f32x4 acc = {0.f, 0.f, 0.f, 0.f};
  const float* wp = Wm + (size_t)(g * HH + j0 + r16) * K + kg * 8;
  const short* ap = Am + (size_t)(bg * 16 + r16) * K + kg * 8;
#pragma unroll 4
  for (int k0 = 0; k0 < K; k0 += 32) {
    float4 w0 = *(const float4*)(wp + k0);
    float4 w1 = *(const float4*)(wp + k0 + 4);
    short8v a = *(const short8v*)(ap + k0);
    short8v bf;
    bf[0] = bfh(w0.x); bf[1] = bfh(w0.y); bf[2] = bfh(w0.z); bf[3] = bfh(w0.w);
    bf[4] = bfh(w1.x); bf[5] = bfh(w1.y); bf[6] = bfh(w1.z); bf[7] = bfh(w1.w);
    acc = __builtin_amdgcn_mfma_f32_16x16x32_bf16(a, bf, acc, 0, 0, 0);
  }
#pragma unroll
  for (int r = 0; r < 4; r++) P[part][g][kg * 4 + r][r16] = acc[r];
  __syncthreads();
  if (w == 0) {
    int col = j0 + r16;
    float bir = b_ih[col] + b_hh[col];
    float biz = b_ih[HH + col] + b_hh[HH + col];
    float bin = b_ih[2 * HH + col], bhn = b_hh[2 * HH + col];
#pragma unroll
    for (int r = 0; r < 4; r++) {
      int m = kg * 4 + r;
      int row = bg * 16 + m;
      float rv = sigmoidf(P[0][0][m][r16] + P[1][0][m][r16] + bir);
      float zv = sigmoidf(P[0][1][m][r16] + P[1][1][m][r16] + biz);
      float nv = tanhf(P[0][2][m][r16] + bin + rv * (P[1][2][m][r16] + bhn));
      float h = (1.f - zv) * nv + zv * hprev[(size_t)row * HH + col];
      hout_f[(size_t)row * HH + col] = h;
      hout_o[(size_t)row * HH + col] = h;
      hout_b[(size_t)row * bstride + col] = bfh(h);
    }
  }
}

// ---------------- tanh(scores): one wave per (b,t); sdot/cc fused in ----------------
__global__ void scores_kernel(const float* __restrict__ enc, const float* __restrict__ cov,
                              const float* __restrict__ aW, const float* __restrict__ ab,
                              const float* __restrict__ covW, const float* __restrict__ covb,
                              const float* __restrict__ s, float* __restrict__ ts) {
  int b = blockIdx.y;
  int wid = threadIdx.x >> 6, lane = threadIdx.x & 63;
  int t = blockIdx.x * 4 + wid;
  int i8 = lane * 8;
  const float* e = enc + ((size_t)b * TT + t) * HH + i8;
  float4 a0 = *(const float4*)&aW[i8],        a1 = *(const float4*)&aW[i8 + 4];
  float4 b0 = *(const float4*)&aW[HH + i8],   b1 = *(const float4*)&aW[HH + i8 + 4];
  float4 c0 = *(const float4*)&aW[2*HH + i8], c1 = *(const float4*)&aW[2*HH + i8 + 4];
  float4 s0 = *(const float4*)&s[(size_t)b * HH + i8], s1 = *(const float4*)&s[(size_t)b * HH + i8 + 4];
  float4 w0 = *(const float4*)&covW[i8],      w1 = *(const float4*)&covW[i8 + 4];
  float4 v0 = *(const float4*)&covb[i8],      v1 = *(const float4*)&covb[i8 + 4];
  float covbt = cov[b * TT + t];
  float p1 = dot4(*(const float4*)&e[0], a0) + dot4(*(const float4*)&e[4], a1)
           + dot4(s0, b0) + dot4(s1, b1)
           + dot4(v0, c0) + dot4(v1, c1);
  float p2 = dot4(w0, c0) + dot4(w1, c1);
  float d = wredsum(p1 + covbt * p2);
  if (lane == 0) ts[b * TT + t] = tanhf(d + ab[0]);
}

// ---------------- attention softmax over T + new_coverage + scatter + loss ----------------
__global__ void attn_kernel(const float* __restrict__ ts, const float* __restrict__ cov,
                            const int* __restrict__ src,
                            float* __restrict__ wattn, float* __restrict__ dout,
                            float* __restrict__ outc) {
  int b = blockIdx.x, tid = threadIdx.x;
  int lane = tid & 63, wid = tid >> 6;
  __shared__ float sred[8];
  __shared__ float bval[2];
  float v = (tid < TT) ? ts[b * TT + tid] : -1e30f;
  float wm = wredmax(v);
  if (lane == 0) sred[wid] = wm;
  __syncthreads();
  if (wid == 0) {
    float r = (lane < 8) ? sred[lane] : -1e30f;
    r = wredmax(r);
    if (lane == 0) bval[0] = r;
  }
  __syncthreads();
  float m = bval[0];
  float e = (tid < TT) ? expf(v - m) : 0.f;
  float wsm = wredsum(e);
  __syncthreads();
  if (lane == 0) sred[wid] = wsm;
  __syncthreads();
  if (wid == 0) {
    float r = (lane < 8) ? sred[lane] : 0.f;
    r = wredsum(r);
    if (lane == 0) bval[1] = r;
  }
  __syncthreads();
  float denom = bval[1];
  float a = e / denom;
  float lp = 0.f;
  if (tid < TT) {
    wattn[b * TT + tid] = a;
    dout[OFF_ATTN + b * TT + tid] = a;
    float c = cov[b * TT + tid];
    dout[OFF_NEWCOV + b * TT + tid] = c + a;
    lp = fminf(a, c);
    atomicAdd(&outc[(size_t)b * VV + src[b * TT + tid]], a);
  }
  float wl = wredsum(lp);
  __syncthreads();
  if (lane == 0) sred[wid] = wl;
  __syncthreads();
  if (wid == 0) {
    float r = (lane < 8) ? sred[lane] : 0.f;
    r = wredsum(r);
    if (lane == 0) atomicAdd(&dout[OFF_LOSS], r);
  }
}

// ---------------- ctx partials: grid (b, chunk); 512 threads ----------------
__global__ void ctx_part_kernel(const float* __restrict__ enc, const float* __restrict__ attn,
                                float* __restrict__ ctxp) {
  int b = blockIdx.x, c = blockIdx.y;
  int h = threadIdx.x;
  __shared__ float as[TT / NCH];
  if (h < TT / NCH) as[h] = attn[b * TT + c * (TT / NCH) + h];
  __syncthreads();
  const float* e = enc + ((size_t)b * TT + c * (TT / NCH)) * HH + h;
  float acc = 0.f;
#pragma unroll 10
  for (int t = 0; t < TT / NCH; t++) acc += as[t] * e[(size_t)t * HH];
  ctxp[((size_t)b * NCH + c) * HH + h] = acc;
}

// ---------------- ctx reduce + bf16 into A1 + p_gen ----------------
__global__ void ctxred_pgen_kernel(const float* __restrict__ ctxp, const float* __restrict__ s,
                                   const float* __restrict__ embt, const int* __restrict__ ids,
                                   const float* __restrict__ gW, const float* __restrict__ gb,
                                   short* __restrict__ a1, float* __restrict__ pgen) {
  int b = blockIdx.x, tid = threadIdx.x;     // 512 threads
  int lane = tid & 63, wid = tid >> 6;
  __shared__ float sred[8];
  float acc = 0.f;
#pragma unroll
  for (int c = 0; c < NCH; c++) acc += ctxp[((size_t)b * NCH + c) * HH + tid];
  a1[(size_t)b * H4 + HH + tid] = bfh(acc);
  float part = acc * gW[tid] + s[b * HH + tid] * gW[HH + tid];
  if (tid < EE) part += embt[(size_t)ids[b] * EE + tid] * gW[2 * HH + tid];
  float w = wredsum(part);
  if (lane == 0) sred[wid] = w;
  __syncthreads();
  if (wid == 0) {
    float r = (lane < 8) ? sred[lane] : 0.f;
    r = wredsum(r);
    if (lane == 0) pgen[b] = sigmoidf(r + gb[0]);
  }
}

// ---------------- fc1 via MFMA, K-split 4: ni = tanh(A1 @ W^T + b) -> bf16 ----------------
__global__ __launch_bounds__(256) void fc1_kernel(const short* __restrict__ a1,
                                                  const float* __restrict__ W,
                                                  const float* __restrict__ bias,
                                                  short* __restrict__ nib) {
  __shared__ float part[4096];
  const int w = threadIdx.x >> 6;
  const int lane = threadIdx.x & 63;
  const int r16 = lane & 15, kg = lane >> 4;
  const int v0 = blockIdx.x * 16;
  const int kb = w * 256;

  f32x4 acc0 = {0.f,0.f,0.f,0.f}, acc1 = {0.f,0.f,0.f,0.f};
  f32x4 acc2 = {0.f,0.f,0.f,0.f}, acc3 = {0.f,0.f,0.f,0.f};
  const float* wp = W + (size_t)(v0 + r16) * H4 + kb + kg * 8;
  const short* ap = a1 + (size_t)r16 * H4 + kb + kg * 8;
#pragma unroll 4
  for (int k0 = 0; k0 < 256; k0 += 32) {
    float4 w0 = *(const float4*)(wp + k0);
    float4 w1 = *(const float4*)(wp + k0 + 4);
    short8v a0 = *(const short8v*)(ap + k0);
    short8v a1v = *(const short8v*)(ap + 16 * H4 + k0);
    short8v a2 = *(const short8v*)(ap + 32 * H4 + k0);
    short8v a3 = *(const short8v*)(ap + 48 * H4 + k0);
    short8v bf;
    bf[0] = bfh(w0.x); bf[1] = bfh(w0.y); bf[2] = bfh(w0.z); bf[3] = bfh(w0.w);
    bf[4] = bfh(w1.x); bf[5] = bfh(w1.y); bf[6] = bfh(w1.z); bf[7] = bfh(w1.w);
    acc0 = __builtin_amdgcn_mfma_f32_16x16x32_bf16(a0, bf, acc0, 0, 0, 0);
    acc1 = __builtin_amdgcn_mfma_f32_16x16x32_bf16(a1v, bf, acc1, 0, 0, 0);
    acc2 = __builtin_amdgcn_mfma_f32_16x16x32_bf16(a2, bf, acc2, 0, 0, 0);
    acc3 = __builtin_amdgcn_mfma_f32_16x16x32_bf16(a3, bf, acc3, 0, 0, 0);
  }
  float* pb = part + w * 1024;
#pragma unroll
  for (int r = 0; r < 4; r++) {
    pb[(kg * 4 + r) * 16 + r16]      = acc0[r];
    pb[(16 + kg * 4 + r) * 16 + r16] = acc1[r];
    pb[(32 + kg * 4 + r) * 16 + r16] = acc2[r];
    pb[(48 + kg * 4 + r) * 16 + r16] = acc3[r];
  }
  __syncthreads();
  int idx = threadIdx.x * 4;
  int m = idx >> 4, c0 = idx & 15;
  f32x4 s0 = *(const f32x4*)(part + idx);
  f32x4 s1 = *(const f32x4*)(part + 1024 + idx);
  f32x4 s2 = *(const f32x4*)(part + 2048 + idx);
  f32x4 s3 = *(const f32x4*)(part + 3072 + idx);
  f32x4 bv = *(const f32x4*)(bias + v0 + c0);
  f32x4 o = s0 + s1 + s2 + s3 + bv;
#pragma unroll
  for (int j = 0; j < 4; j++)
    nib[(size_t)m * H4 + v0 + c0 + j] = bfh(tanhf(o[j]));
}

// ---------------- fc2 via MFMA, K-split 4: logits = ni @ W^T + b ----------------
__global__ __launch_bounds__(256, 4) void fc2_kernel(const short* __restrict__ nib,
                                                     const float* __restrict__ W,
                                                     const float* __restrict__ bias,
                                                     float* __restrict__ logits) {
  __shared__ float part[4096];
  const int w = threadIdx.x >> 6;
  const int lane = threadIdx.x & 63;
  const int r16 = lane & 15, kg = lane >> 4;
  const int v0 = blockIdx.x * 16;
  const int kb = w * 256;

  f32x4 acc0 = {0.f,0.f,0.f,0.f}, acc1 = {0.f,0.f,0.f,0.f};
  f32x4 acc2 = {0.f,0.f,0.f,0.f}, acc3 = {0.f,0.f,0.f,0.f};
  const float* wp = W + (size_t)(v0 + r16) * H4 + kb + kg * 8;
  const short* ap = nib + (size_t)r16 * H4 + kb + kg * 8;
#pragma unroll 4
  for (int k0 = 0; k0 < 256; k0 += 32) {
    float4 w0 = *(const float4*)(wp + k0);
    float4 w1 = *(const float4*)(wp + k0 + 4);
    short8v a0 = *(const short8v*)(ap + k0);
    short8v a1 = *(const short8v*)(ap + 16 * H4 + k0);
    short8v a2 = *(const short8v*)(ap + 32 * H4 + k0);
    short8v a3 = *(const short8v*)(ap + 48 * H4 + k0);
    short8v bf;
    bf[0] = bfh(w0.x); bf[1] = bfh(w0.y); bf[2] = bfh(w0.z); bf[3] = bfh(w0.w);
    bf[4] = bfh(w1.x); bf[5] = bfh(w1.y); bf[6] = bfh(w1.z); bf[7] = bfh(w1.w);
    acc0 = __builtin_amdgcn_mfma_f32_16x16x32_bf16(a0, bf, acc0, 0, 0, 0);
    acc1 = __builtin_amdgcn_mfma_f32_16x16x32_bf16(a1, bf, acc1, 0, 0, 0);
    acc2 = __builtin_amdgcn_mfma_f32_16x16x32_bf16(a2, bf, acc2, 0, 0, 0);
    acc3 = __builtin_amdgcn_mfma_f32_16x16x32_bf16(a3, bf, acc3, 0, 0, 0);
  }
  float* pb = part + w * 1024;
#pragma unroll
  for (int r = 0; r < 4; r++) {
    pb[(kg * 4 + r) * 16 + r16]      = acc0[r];
    pb[(16 + kg * 4 + r) * 16 + r16] = acc1[r];
    pb[(32 + kg * 4 + r) * 16 + r16] = acc2[r];
    pb[(48 + kg * 4 + r) * 16 + r16] = acc3[r];
  }
  __syncthreads();
  int idx = threadIdx.x * 4;
  int m = idx >> 4, c0 = idx & 15;
  f32x4 s0 = *(const f32x4*)(part + idx);
  f32x4 s1 = *(const f32x4*)(part + 1024 + idx);
  f32x4 s2 = *(const f32x4*)(part + 2048 + idx);
  f32x4 s3 = *(const f32x4*)(part + 3072 + idx);
  f32x4 bv = *(const f32x4*)(bias + v0 + c0);
  f32x4 o = s0 + s1 + s2 + s3 + bv;
  *(f32x4*)(logits + (size_t)m * VV + v0 + c0) = o;
}

// ---------------- per-row vocab softmax stats ----------------
__global__ void smax_kernel(const float* __restrict__ logits, float* __restrict__ rm,
                            float* __restrict__ rs) {
  int b = blockIdx.x, tid = threadIdx.x;
  int lane = tid & 63, wid = tid >> 6;
  __shared__ float sred[4];
  __shared__ float bval[2];
  const float4* row = (const float4*)(logits + (size_t)b * VV);
  float m = -1e30f;
  for (int i = tid; i < VV / 4; i += 256) {
    float4 l = row[i];
    m = fmaxf(m, fmaxf(fmaxf(l.x, l.y), fmaxf(l.z, l.w)));
  }
  m = wredmax(m);
  if (lane == 0) sred[wid] = m;
  __syncthreads();
  if (wid == 0) {
    float r = (lane < 4) ? sred[lane] : -1e30f;
    r = wredmax(r);
    if (lane == 0) bval[0] = r;
  }
  __syncthreads();
  float bm = bval[0];
  float sacc = 0.f;
  for (int i = tid; i < VV / 4; i += 256) {
    float4 l = row[i];
    sacc += expf(l.x - bm) + expf(l.y - bm) + expf(l.z - bm) + expf(l.w - bm);
  }
  sacc = wredsum(sacc);
  __syncthreads();
  if (lane == 0) sred[wid] = sacc;
  __syncthreads();
  if (wid == 0) {
    float r = (lane < 4) ? sred[lane] : 0.f;
    r = wredsum(r);
    if (lane == 0) { rm[b] = bm; rs[b] = r; }
  }
}

// ---------------- final mix: out = Pvocab*p_gen + copy*(1-p_gen) ----------------
__global__ void final_kernel(const float* __restrict__ logits, const float* __restrict__ rm,
                             const float* __restrict__ rs, const float* __restrict__ pgen,
                             const float* __restrict__ copy, float* __restrict__ out) {
  int i = blockIdx.x * 256 + threadIdx.x;     // over 800000 float4s
  int b = (i * 4) / VV;
  float p = pgen[b], m = rm[b], s = rs[b];
  float4 l = ((const float4*)logits)[i];
  float4 c = ((const float4*)copy)[i];
  float q = 1.f - p;
  float4 o;
  o.x = expf(l.x - m) / s * p + c.x * q;
  o.y = expf(l.y - m) / s * p + c.y * q;
  o.z = expf(l.z - m) / s * p + c.z * q;
  o.w = expf(l.w - m) / s * p + c.w * q;
  ((float4*)out)[i] = o;
}

extern "C" void kernel_launch(void* const* d_in, const int* in_sizes, int n_in,
                              void* d_out, int out_size, void* d_ws, size_t ws_size,
                              hipStream_t stream) {
  const int*   ids  = (const int*)d_in[0];
  const float* preh = (const float*)d_in[1];
  const float* enc  = (const float*)d_in[2];
  const int*   src  = (const int*)d_in[3];
  const float* cov  = (const float*)d_in[4];
  const float* embt = (const float*)d_in[5];
  const float* Wih0 = (const float*)d_in[6];
  const float* Whh0 = (const float*)d_in[7];
  const float* bih0 = (const float*)d_in[8];
  const float* bhh0 = (const float*)d_in[9];
  const float* Wih1 = (const float*)d_in[10];
  const float* Whh1 = (const float*)d_in[11];
  const float* bih1 = (const float*)d_in[12];
  const float* bhh1 = (const float*)d_in[13];
  const float* aW   = (const float*)d_in[14];
  const float* ab   = (const float*)d_in[15];
  const float* covW = (const float*)d_in[16];
  const float* covb = (const float*)d_in[17];
  const float* f1W  = (const float*)d_in[18];
  const float* f1b  = (const float*)d_in[19];
  const float* f2W  = (const float*)d_in[20];
  const float* f2b  = (const float*)d_in[21];
  const float* gW   = (const float*)d_in[22];
  const float* gb   = (const float*)d_in[23];
  float* out = (float*)d_out;
  float* ws  = (float*)d_ws;

  zero_prep_kernel<<<3125, 256, 0, stream>>>(out + OFF_COPY, out + OFF_LOSS,
                                             embt, ids, preh,
                                             (short*)(ws + WS_AX0), (short*)(ws + WS_AH0),
                                             (short*)(ws + WS_AH1));
  gru_mfma_kernel<EE><<<128, 384, 0, stream>>>(
      (const short*)(ws + WS_AX0), (const short*)(ws + WS_AH0),
      Wih0, Whh0, bih0, bhh0, preh,
      out + OFF_CURHID, out + OFF_CURHID, (short*)(ws + WS_AX1), HH);
  gru_mfma_kernel<HH><<<128, 384, 0, stream>>>(
      (const short*)(ws + WS_AX1), (const short*)(ws + WS_AH1),
      Wih1, Whh1, bih1, bhh1, preh + BB * HH,
      ws + WS_S, out + OFF_CURHID + BB * HH, (short*)(ws + WS_A1), H4);
  scores_kernel<<<dim3(100, 64), 256, 0, stream>>>(enc, cov, aW, ab, covW, covb,
                                                   ws + WS_S, ws + WS_TS);
  attn_kernel<<<64, 512, 0, stream>>>(ws + WS_TS, cov, src, ws + WS_ATTN, out,
                                      out + OFF_COPY);
  ctx_part_kernel<<<dim3(64, NCH), 512, 0, stream>>>(enc, ws + WS_ATTN, ws + WS_CTXP);
  ctxred_pgen_kernel<<<64, 512, 0, stream>>>(ws + WS_CTXP, ws + WS_S, embt, ids, gW, gb,
                                             (short*)(ws + WS_A1), ws + WS_PGEN);
  fc1_kernel<<<64, 256, 0, stream>>>((const short*)(ws + WS_A1), f1W, f1b,
                                     (short*)(ws + WS_NIB));
  fc2_kernel<<<3125, 256, 0, stream>>>((const short*)(ws + WS_NIB), f2W, f2b,
                                       ws + WS_LOGITS);
  smax_kernel<<<64, 256, 0, stream>>>(ws + WS_LOGITS, ws + WS_RM, ws + WS_RS);
  final_kernel<<<3125, 256, 0, stream>>>(ws + WS_LOGITS, ws + WS_RM, ws + WS_RS,
                                         ws + WS_PGEN, out + OFF_COPY, out);
}

// Round 6
// 157.997 us; speedup vs baseline: 3.5911x; 1.1928x over previous
//
#include <hip/hip_runtime.h>
#include <hip/hip_bf16.h>
#include <cstddef>

#define BB 64
#define TT 400
#define EE 128
#define HH 512
#define H4 1024
#define VV 50000
#define NCH 8                                  // ctx T-chunks
#define LSTR 264                               // LDS row stride in shorts (256+8 pad)

// ---- d_out layout (floats), reference return order ----
#define OFF_OUT     0
#define OFF_CURHID  (BB*VV)                    // 3,200,000
#define OFF_ATTN    (OFF_CURHID + 2*BB*HH)     // 3,265,536
#define OFF_COPY    (OFF_ATTN + BB*TT)         // 3,291,136
#define OFF_NEWCOV  (OFF_COPY + BB*VV)         // 6,491,136
#define OFF_LOSS    (OFF_NEWCOV + BB*TT)       // 6,516,736

// ---- workspace layout (floats; bf16 buffers noted) ----
#define WS_S      0                            // f32 s 64x512
#define WS_TS     (WS_S + BB*HH)
#define WS_ATTN   (WS_TS + BB*TT)
#define WS_NIB    (WS_ATTN + BB*TT)            // bf16 ni 64x1024
#define WS_A1     (WS_NIB + BB*H4/2)           // bf16 [s|ctx] 64x1024
#define WS_AX0    (WS_A1 + BB*H4/2)            // bf16 emb 64x128
#define WS_AH0    (WS_AX0 + BB*EE/2)           // bf16 h_prev0 64x512
#define WS_AH1    (WS_AH0 + BB*HH/2)           // bf16 h_prev1 64x512
#define WS_AX1    (WS_AH1 + BB*HH/2)           // bf16 h0 64x512
#define WS_PGEN   (WS_AX1 + BB*HH/2)
#define WS_RM     (WS_PGEN + 64)
#define WS_RS     (WS_RM + 64)
#define WS_CTXP   (WS_RS + 64)                 // f32 partial ctx 64x8x512 (1 MB)
#define WS_LOGITS (WS_CTXP + BB*NCH*HH)        // f32 64x50000

typedef __attribute__((ext_vector_type(8))) short short8v;
typedef __attribute__((ext_vector_type(4))) short short4v;
typedef __attribute__((ext_vector_type(4))) float f32x4;

__device__ __forceinline__ float wredsum(float v) {
#pragma unroll
  for (int o = 32; o > 0; o >>= 1) v += __shfl_down(v, o, 64);
  return v;
}
__device__ __forceinline__ float wredmax(float v) {
#pragma unroll
  for (int o = 32; o > 0; o >>= 1) v = fmaxf(v, __shfl_down(v, o, 64));
  return v;
}
__device__ __forceinline__ float dot4(float4 a, float4 b) {
  return a.x*b.x + a.y*b.y + a.z*b.z + a.w*b.w;
}
__device__ __forceinline__ float sigmoidf(float x) { return 1.f / (1.f + expf(-x)); }
__device__ __forceinline__ short bfh(float f) {
  union { __hip_bfloat16 h; short s; } u; u.h = __float2bfloat16(f); return u.s;
}

// ---------------- zero copy_prob + loss, and bf16 prep for GRU A-operands ----------------
__global__ void zero_prep_kernel(float* __restrict__ p, float* __restrict__ loss,
                                 const float* __restrict__ embt, const int* __restrict__ ids,
                                 const float* __restrict__ preh,
                                 short* __restrict__ ax0, short* __restrict__ ah0,
                                 short* __restrict__ ah1) {
  int i = blockIdx.x * 256 + threadIdx.x;   // 800000 float4s
  ((float4*)p)[i] = make_float4(0.f, 0.f, 0.f, 0.f);
  if (i == 0) loss[0] = 0.f;
  if (i < BB * EE) {
    int b = i >> 7, k = i & 127;
    ax0[i] = bfh(embt[(size_t)ids[b] * EE + k]);
  } else if (i < BB * EE + 2 * BB * HH) {
    int j = i - BB * EE;
    if (j < BB * HH) ah0[j] = bfh(preh[j]);
    else ah1[j - BB * HH] = bfh(preh[j]);
  }
}

// ---------------- GRU layer via MFMA ----------------
// 128 blocks = 32 col-frags x 4 batch-groups; 6 waves = {r,z,n} x {ih,hh}.
template<int KX>
__global__ __launch_bounds__(384) void gru_mfma_kernel(
    const short* __restrict__ Ax, const short* __restrict__ Ah,
    const float* __restrict__ W_ih, const float* __restrict__ W_hh,
    const float* __restrict__ b_ih, const float* __restrict__ b_hh,
    const float* __restrict__ hprev,
    float* __restrict__ hout_f, float* __restrict__ hout_o,
    short* __restrict__ hout_b, int bstride) {
  __shared__ float P[2][3][16][16];
  const int w = threadIdx.x >> 6;             // 0..5
  const int lane = threadIdx.x & 63;
  const int r16 = lane & 15, kg = lane >> 4;
  const int j0 = (blockIdx.x & 31) * 16;      // gate-col fragment
  const int bg = blockIdx.x >> 5;             // batch group (16 rows)
  const int part = (w >= 3) ? 1 : 0;          // 0 = ih, 1 = hh
  const int g = w - part * 3;                 // gate r/z/n
  const int K = part ? HH : KX;
  const float* Wm = part ? W_hh : W_ih;
  const short* Am = part ? Ah : Ax;

  f32x4 acc = {0.f, 0.f, 0.f, 0.f};
  const float* wp = Wm + (size_t)(g * HH + j0 + r16) * K + kg * 8;
  const short* ap = Am + (size_t)(bg * 16 + r16) * K + kg * 8;
#pragma unroll 4
  for (int k0 = 0; k0 < K; k0 += 32) {
    float4 w0 = *(const float4*)(wp + k0);
    float4 w1 = *(const float4*)(wp + k0 + 4);
    short8v a = *(const short8v*)(ap + k0);
    short8v bf;
    bf[0] = bfh(w0.x); bf[1] = bfh(w0.y); bf[2] = bfh(w0.z); bf[3] = bfh(w0.w);
    bf[4] = bfh(w1.x); bf[5] = bfh(w1.y); bf[6] = bfh(w1.z); bf[7] = bfh(w1.w);
    acc = __builtin_amdgcn_mfma_f32_16x16x32_bf16(a, bf, acc, 0, 0, 0);
  }
#pragma unroll
  for (int r = 0; r < 4; r++) P[part][g][kg * 4 + r][r16] = acc[r];
  __syncthreads();
  if (w == 0) {
    int col = j0 + r16;
    float bir = b_ih[col] + b_hh[col];
    float biz = b_ih[HH + col] + b_hh[HH + col];
    float bin = b_ih[2 * HH + col], bhn = b_hh[2 * HH + col];
#pragma unroll
    for (int r = 0; r < 4; r++) {
      int m = kg * 4 + r;
      int row = bg * 16 + m;
      float rv = sigmoidf(P[0][0][m][r16] + P[1][0][m][r16] + bir);
      float zv = sigmoidf(P[0][1][m][r16] + P[1][1][m][r16] + biz);
      float nv = tanhf(P[0][2][m][r16] + bin + rv * (P[1][2][m][r16] + bhn));
      float h = (1.f - zv) * nv + zv * hprev[(size_t)row * HH + col];
      hout_f[(size_t)row * HH + col] = h;
      hout_o[(size_t)row * HH + col] = h;
      hout_b[(size_t)row * bstride + col] = bfh(h);
    }
  }
}

// ---------------- tanh(scores): one wave per (b,t); sdot/cc fused in ----------------
__global__ void scores_kernel(const float* __restrict__ enc, const float* __restrict__ cov,
                              const float* __restrict__ aW, const float* __restrict__ ab,
                              const float* __restrict__ covW, const float* __restrict__ covb,
                              const float* __restrict__ s, float* __restrict__ ts) {
  int b = blockIdx.y;
  int wid = threadIdx.x >> 6, lane = threadIdx.x & 63;
  int t = blockIdx.x * 4 + wid;
  int i8 = lane * 8;
  const float* e = enc + ((size_t)b * TT + t) * HH + i8;
  float4 a0 = *(const float4*)&aW[i8],        a1 = *(const float4*)&aW[i8 + 4];
  float4 b0 = *(const float4*)&aW[HH + i8],   b1 = *(const float4*)&aW[HH + i8 + 4];
  float4 c0 = *(const float4*)&aW[2*HH + i8], c1 = *(const float4*)&aW[2*HH + i8 + 4];
  float4 s0 = *(const float4*)&s[(size_t)b * HH + i8], s1 = *(const float4*)&s[(size_t)b * HH + i8 + 4];
  float4 w0 = *(const float4*)&covW[i8],      w1 = *(const float4*)&covW[i8 + 4];
  float4 v0 = *(const float4*)&covb[i8],      v1 = *(const float4*)&covb[i8 + 4];
  float covbt = cov[b * TT + t];
  float p1 = dot4(*(const float4*)&e[0], a0) + dot4(*(const float4*)&e[4], a1)
           + dot4(s0, b0) + dot4(s1, b1)
           + dot4(v0, c0) + dot4(v1, c1);
  float p2 = dot4(w0, c0) + dot4(w1, c1);
  float d = wredsum(p1 + covbt * p2);
  if (lane == 0) ts[b * TT + t] = tanhf(d + ab[0]);
}

// ---------------- attention softmax over T + new_coverage + scatter + loss ----------------
__global__ void attn_kernel(const float* __restrict__ ts, const float* __restrict__ cov,
                            const int* __restrict__ src,
                            float* __restrict__ wattn, float* __restrict__ dout,
                            float* __restrict__ outc) {
  int b = blockIdx.x, tid = threadIdx.x;
  int lane = tid & 63, wid = tid >> 6;
  __shared__ float sred[8];
  __shared__ float bval[2];
  float v = (tid < TT) ? ts[b * TT + tid] : -1e30f;
  float wm = wredmax(v);
  if (lane == 0) sred[wid] = wm;
  __syncthreads();
  if (wid == 0) {
    float r = (lane < 8) ? sred[lane] : -1e30f;
    r = wredmax(r);
    if (lane == 0) bval[0] = r;
  }
  __syncthreads();
  float m = bval[0];
  float e = (tid < TT) ? expf(v - m) : 0.f;
  float wsm = wredsum(e);
  __syncthreads();
  if (lane == 0) sred[wid] = wsm;
  __syncthreads();
  if (wid == 0) {
    float r = (lane < 8) ? sred[lane] : 0.f;
    r = wredsum(r);
    if (lane == 0) bval[1] = r;
  }
  __syncthreads();
  float denom = bval[1];
  float a = e / denom;
  float lp = 0.f;
  if (tid < TT) {
    wattn[b * TT + tid] = a;
    dout[OFF_ATTN + b * TT + tid] = a;
    float c = cov[b * TT + tid];
    dout[OFF_NEWCOV + b * TT + tid] = c + a;
    lp = fminf(a, c);
    atomicAdd(&outc[(size_t)b * VV + src[b * TT + tid]], a);
  }
  float wl = wredsum(lp);
  __syncthreads();
  if (lane == 0) sred[wid] = wl;
  __syncthreads();
  if (wid == 0) {
    float r = (lane < 8) ? sred[lane] : 0.f;
    r = wredsum(r);
    if (lane == 0) atomicAdd(&dout[OFF_LOSS], r);
  }
}

// ---------------- ctx partials: grid (b, chunk); 512 threads ----------------
__global__ void ctx_part_kernel(const float* __restrict__ enc, const float* __restrict__ attn,
                                float* __restrict__ ctxp) {
  int b = blockIdx.x, c = blockIdx.y;
  int h = threadIdx.x;
  __shared__ float as[TT / NCH];
  if (h < TT / NCH) as[h] = attn[b * TT + c * (TT / NCH) + h];
  __syncthreads();
  const float* e = enc + ((size_t)b * TT + c * (TT / NCH)) * HH + h;
  float acc = 0.f;
#pragma unroll 10
  for (int t = 0; t < TT / NCH; t++) acc += as[t] * e[(size_t)t * HH];
  ctxp[((size_t)b * NCH + c) * HH + h] = acc;
}

// ---------------- ctx reduce + bf16 into A1 + p_gen ----------------
__global__ void ctxred_pgen_kernel(const float* __restrict__ ctxp, const float* __restrict__ s,
                                   const float* __restrict__ embt, const int* __restrict__ ids,
                                   const float* __restrict__ gW, const float* __restrict__ gb,
                                   short* __restrict__ a1, float* __restrict__ pgen) {
  int b = blockIdx.x, tid = threadIdx.x;     // 512 threads
  int lane = tid & 63, wid = tid >> 6;
  __shared__ float sred[8];
  float acc = 0.f;
#pragma unroll
  for (int c = 0; c < NCH; c++) acc += ctxp[((size_t)b * NCH + c) * HH + tid];
  a1[(size_t)b * H4 + HH + tid] = bfh(acc);
  float part = acc * gW[tid] + s[b * HH + tid] * gW[HH + tid];
  if (tid < EE) part += embt[(size_t)ids[b] * EE + tid] * gW[2 * HH + tid];
  float w = wredsum(part);
  if (lane == 0) sred[wid] = w;
  __syncthreads();
  if (wid == 0) {
    float r = (lane < 8) ? sred[lane] : 0.f;
    r = wredsum(r);
    if (lane == 0) pgen[b] = sigmoidf(r + gb[0]);
  }
}

// ---------------- fc1 via MFMA, K-split 4: ni = tanh(A1 @ W^T + b) -> bf16 ----------------
__global__ __launch_bounds__(256) void fc1_kernel(const short* __restrict__ a1,
                                                  const float* __restrict__ W,
                                                  const float* __restrict__ bias,
                                                  short* __restrict__ nib) {
  __shared__ float part[4096];
  const int w = threadIdx.x >> 6;
  const int lane = threadIdx.x & 63;
  const int r16 = lane & 15, kg = lane >> 4;
  const int v0 = blockIdx.x * 16;
  const int kb = w * 256;

  f32x4 acc0 = {0.f,0.f,0.f,0.f}, acc1 = {0.f,0.f,0.f,0.f};
  f32x4 acc2 = {0.f,0.f,0.f,0.f}, acc3 = {0.f,0.f,0.f,0.f};
  const float* wp = W + (size_t)(v0 + r16) * H4 + kb + kg * 8;
  const short* ap = a1 + (size_t)r16 * H4 + kb + kg * 8;
#pragma unroll 4
  for (int k0 = 0; k0 < 256; k0 += 32) {
    float4 w0 = *(const float4*)(wp + k0);
    float4 w1 = *(const float4*)(wp + k0 + 4);
    short8v a0 = *(const short8v*)(ap + k0);
    short8v a1v = *(const short8v*)(ap + 16 * H4 + k0);
    short8v a2 = *(const short8v*)(ap + 32 * H4 + k0);
    short8v a3 = *(const short8v*)(ap + 48 * H4 + k0);
    short8v bf;
    bf[0] = bfh(w0.x); bf[1] = bfh(w0.y); bf[2] = bfh(w0.z); bf[3] = bfh(w0.w);
    bf[4] = bfh(w1.x); bf[5] = bfh(w1.y); bf[6] = bfh(w1.z); bf[7] = bfh(w1.w);
    acc0 = __builtin_amdgcn_mfma_f32_16x16x32_bf16(a0, bf, acc0, 0, 0, 0);
    acc1 = __builtin_amdgcn_mfma_f32_16x16x32_bf16(a1v, bf, acc1, 0, 0, 0);
    acc2 = __builtin_amdgcn_mfma_f32_16x16x32_bf16(a2, bf, acc2, 0, 0, 0);
    acc3 = __builtin_amdgcn_mfma_f32_16x16x32_bf16(a3, bf, acc3, 0, 0, 0);
  }
  float* pb = part + w * 1024;
#pragma unroll
  for (int r = 0; r < 4; r++) {
    pb[(kg * 4 + r) * 16 + r16]      = acc0[r];
    pb[(16 + kg * 4 + r) * 16 + r16] = acc1[r];
    pb[(32 + kg * 4 + r) * 16 + r16] = acc2[r];
    pb[(48 + kg * 4 + r) * 16 + r16] = acc3[r];
  }
  __syncthreads();
  int idx = threadIdx.x * 4;
  int m = idx >> 4, c0 = idx & 15;
  f32x4 s0 = *(const f32x4*)(part + idx);
  f32x4 s1 = *(const f32x4*)(part + 1024 + idx);
  f32x4 s2 = *(const f32x4*)(part + 2048 + idx);
  f32x4 s3 = *(const f32x4*)(part + 3072 + idx);
  f32x4 bv = *(const f32x4*)(bias + v0 + c0);
  f32x4 o = s0 + s1 + s2 + s3 + bv;
#pragma unroll
  for (int j = 0; j < 4; j++)
    nib[(size_t)m * H4 + v0 + c0 + j] = bfh(tanhf(o[j]));
}

// ---------------- fc2 v3: LDS-staged MFMA GEMM, tile 64M x 64N, K-step 256 ----------------
// Coalesced staging: per load instruction 16 rows x full 64B sectors (100% util).
// LDS rows padded to 264 shorts to break power-of-2 bank aliasing.
__global__ __launch_bounds__(256) void fc2_kernel(const short* __restrict__ nib,
                                                  const float* __restrict__ W,
                                                  const float* __restrict__ bias,
                                                  float* __restrict__ logits) {
  __shared__ short Wl[64 * LSTR];   // 33 KB
  __shared__ short Al[64 * LSTR];   // 33 KB
  const int tid = threadIdx.x;
  const int w = tid >> 6, lane = tid & 63;
  const int r16 = lane & 15, kg = lane >> 4;
  const int v0 = blockIdx.x * 64;
  const int srow = tid >> 2, quad = tid & 3;          // staging role
  const int vr = min(v0 + srow, VV - 1);              // clamp OOB vocab rows

  f32x4 acc[4];
#pragma unroll
  for (int i = 0; i < 4; i++) acc[i] = (f32x4){0.f, 0.f, 0.f, 0.f};

  for (int k0 = 0; k0 < H4; k0 += 256) {
    __syncthreads();
    // ---- stage W tile [64v][256k] f32 -> bf16 LDS (coalesced 64B runs) ----
    {
      const float* src = W + (size_t)vr * H4 + k0 + quad * 4;
      char* dst = (char*)Wl + srow * (LSTR * 2) + quad * 8;
#pragma unroll
      for (int j = 0; j < 16; j++) {
        float4 f = *(const float4*)(src + j * 16);
        short4v h; h[0] = bfh(f.x); h[1] = bfh(f.y); h[2] = bfh(f.z); h[3] = bfh(f.w);
        *(short4v*)(dst + j * 32) = h;
      }
      // ---- stage A tile [64m][256k] bf16 (already bf16, straight copy) ----
      const short* asrc = nib + (size_t)srow * H4 + k0 + quad * 8;
      char* adst = (char*)Al + srow * (LSTR * 2) + quad * 16;
#pragma unroll
      for (int j = 0; j < 8; j++)
        *(short8v*)(adst + j * 64) = *(const short8v*)(asrc + j * 32);
    }
    __syncthreads();
    // ---- compute: 8 sub-k of 32; wave w owns 16 vocab cols ----
#pragma unroll
    for (int s = 0; s < 8; s++) {
      short8v wf = *(const short8v*)((char*)Wl + (w * 16 + r16) * (LSTR * 2) + s * 64 + kg * 16);
#pragma unroll
      for (int i = 0; i < 4; i++) {
        short8v af = *(const short8v*)((char*)Al + (i * 16 + r16) * (LSTR * 2) + s * 64 + kg * 16);
        acc[i] = __builtin_amdgcn_mfma_f32_16x16x32_bf16(af, wf, acc[i], 0, 0, 0);
      }
    }
  }

  // ---- epilogue: transpose through LDS, coalesced float4 stores ----
  __syncthreads();
  float* sc = (float*)Wl;                             // 16 KB scratch
#pragma unroll
  for (int i = 0; i < 4; i++)
#pragma unroll
    for (int r = 0; r < 4; r++)
      sc[(i * 16 + kg * 4 + r) * 64 + w * 16 + r16] = acc[i][r];
  __syncthreads();
  int m = tid >> 2, c = (tid & 3) * 16;
  const float* scp = sc + m * 64 + c;
#pragma unroll
  for (int j = 0; j < 4; j++) {
    int col = v0 + c + j * 4;
    if (col < VV) {
      float4 s = *(const float4*)(scp + j * 4);
      float4 bv = *(const float4*)(bias + col);
      *(float4*)(logits + (size_t)m * VV + col) =
          make_float4(s.x + bv.x, s.y + bv.y, s.z + bv.z, s.w + bv.w);
    }
  }
}

// ---------------- per-row vocab softmax stats ----------------
__global__ void smax_kernel(const float* __restrict__ logits, float* __restrict__ rm,
                            float* __restrict__ rs) {
  int b = blockIdx.x, tid = threadIdx.x;
  int lane = tid & 63, wid = tid >> 6;
  __shared__ float sred[4];
  __shared__ float bval[2];
  const float4* row = (const float4*)(logits + (size_t)b * VV);
  float m = -1e30f;
  for (int i = tid; i < VV / 4; i += 256) {
    float4 l = row[i];
    m = fmaxf(m, fmaxf(fmaxf(l.x, l.y), fmaxf(l.z, l.w)));
  }
  m = wredmax(m);
  if (lane == 0) sred[wid] = m;
  __syncthreads();
  if (wid == 0) {
    float r = (lane < 4) ? sred[lane] : -1e30f;
    r = wredmax(r);
    if (lane == 0) bval[0] = r;
  }
  __syncthreads();
  float bm = bval[0];
  float sacc = 0.f;
  for (int i = tid; i < VV / 4; i += 256) {
    float4 l = row[i];
    sacc += expf(l.x - bm) + expf(l.y - bm) + expf(l.z - bm) + expf(l.w - bm);
  }
  sacc = wredsum(sacc);
  __syncthreads();
  if (lane == 0) sred[wid] = sacc;
  __syncthreads();
  if (wid == 0) {
    float r = (lane < 4) ? sred[lane] : 0.f;
    r = wredsum(r);
    if (lane == 0) { rm[b] = bm; rs[b] = r; }
  }
}

// ---------------- final mix: out = Pvocab*p_gen + copy*(1-p_gen) ----------------
__global__ void final_kernel(const float* __restrict__ logits, const float* __restrict__ rm,
                             const float* __restrict__ rs, const float* __restrict__ pgen,
                             const float* __restrict__ copy, float* __restrict__ out) {
  int i = blockIdx.x * 256 + threadIdx.x;     // over 800000 float4s
  int b = (i * 4) / VV;
  float p = pgen[b], m = rm[b], s = rs[b];
  float4 l = ((const float4*)logits)[i];
  float4 c = ((const float4*)copy)[i];
  float q = 1.f - p;
  float4 o;
  o.x = expf(l.x - m) / s * p + c.x * q;
  o.y = expf(l.y - m) / s * p + c.y * q;
  o.z = expf(l.z - m) / s * p + c.z * q;
  o.w = expf(l.w - m) / s * p + c.w * q;
  ((float4*)out)[i] = o;
}

extern "C" void kernel_launch(void* const* d_in, const int* in_sizes, int n_in,
                              void* d_out, int out_size, void* d_ws, size_t ws_size,
                              hipStream_t stream) {
  const int*   ids  = (const int*)d_in[0];
  const float* preh = (const float*)d_in[1];
  const float* enc  = (const float*)d_in[2];
  const int*   src  = (const int*)d_in[3];
  const float* cov  = (const float*)d_in[4];
  const float* embt = (const float*)d_in[5];
  const float* Wih0 = (const float*)d_in[6];
  const float* Whh0 = (const float*)d_in[7];
  const float* bih0 = (const float*)d_in[8];
  const float* bhh0 = (const float*)d_in[9];
  const float* Wih1 = (const float*)d_in[10];
  const float* Whh1 = (const float*)d_in[11];
  const float* bih1 = (const float*)d_in[12];
  const float* bhh1 = (const float*)d_in[13];
  const float* aW   = (const float*)d_in[14];
  const float* ab   = (const float*)d_in[15];
  const float* covW = (const float*)d_in[16];
  const float* covb = (const float*)d_in[17];
  const float* f1W  = (const float*)d_in[18];
  const float* f1b  = (const float*)d_in[19];
  const float* f2W  = (const float*)d_in[20];
  const float* f2b  = (const float*)d_in[21];
  const float* gW   = (const float*)d_in[22];
  const float* gb   = (const float*)d_in[23];
  float* out = (float*)d_out;
  float* ws  = (float*)d_ws;

  zero_prep_kernel<<<3125, 256, 0, stream>>>(out + OFF_COPY, out + OFF_LOSS,
                                             embt, ids, preh,
                                             (short*)(ws + WS_AX0), (short*)(ws + WS_AH0),
                                             (short*)(ws + WS_AH1));
  gru_mfma_kernel<EE><<<128, 384, 0, stream>>>(
      (const short*)(ws + WS_AX0), (const short*)(ws + WS_AH0),
      Wih0, Whh0, bih0, bhh0, preh,
      out + OFF_CURHID, out + OFF_CURHID, (short*)(ws + WS_AX1), HH);
  gru_mfma_kernel<HH><<<128, 384, 0, stream>>>(
      (const short*)(ws + WS_AX1), (const short*)(ws + WS_AH1),
      Wih1, Whh1, bih1, bhh1, preh + BB * HH,
      ws + WS_S, out + OFF_CURHID + BB * HH, (short*)(ws + WS_A1), H4);
  scores_kernel<<<dim3(100, 64), 256, 0, stream>>>(enc, cov, aW, ab, covW, covb,
                                                   ws + WS_S, ws + WS_TS);
  attn_kernel<<<64, 512, 0, stream>>>(ws + WS_TS, cov, src, ws + WS_ATTN, out,
                                      out + OFF_COPY);
  ctx_part_kernel<<<dim3(64, NCH), 512, 0, stream>>>(enc, ws + WS_ATTN, ws + WS_CTXP);
  ctxred_pgen_kernel<<<64, 512, 0, stream>>>(ws + WS_CTXP, ws + WS_S, embt, ids, gW, gb,
                                             (short*)(ws + WS_A1), ws + WS_PGEN);
  fc1_kernel<<<64, 256, 0, stream>>>((const short*)(ws + WS_A1), f1W, f1b,
                                     (short*)(ws + WS_NIB));
  fc2_kernel<<<782, 256, 0, stream>>>((const short*)(ws + WS_NIB), f2W, f2b,
                                      ws + WS_LOGITS);
  smax_kernel<<<64, 256, 0, stream>>>(ws + WS_LOGITS, ws + WS_RM, ws + WS_RS);
  final_kernel<<<3125, 256, 0, stream>>>(ws + WS_LOGITS, ws + WS_RM, ws + WS_RS,
                                         ws + WS_PGEN, out + OFF_COPY, out);
}

// Round 7
// 153.305 us; speedup vs baseline: 3.7010x; 1.0306x over previous
//
#include <hip/hip_runtime.h>
#include <hip/hip_bf16.h>
#include <cstddef>

#define BB 64
#define TT 400
#define EE 128
#define HH 512
#define H4 1024
#define VV 50000
#define NCH 8                                  // ctx T-chunks
#define LSTR 136                               // fc2 LDS row stride in shorts (128+8 pad)

// ---- d_out layout (floats), reference return order ----
#define OFF_OUT     0
#define OFF_CURHID  (BB*VV)                    // 3,200,000
#define OFF_ATTN    (OFF_CURHID + 2*BB*HH)     // 3,265,536
#define OFF_COPY    (OFF_ATTN + BB*TT)         // 3,291,136
#define OFF_NEWCOV  (OFF_COPY + BB*VV)         // 6,491,136
#define OFF_LOSS    (OFF_NEWCOV + BB*TT)       // 6,516,736

// ---- workspace layout (floats; bf16 buffers noted) ----
#define WS_S      0                            // f32 s 64x512
#define WS_TS     (WS_S + BB*HH)
#define WS_ATTN   (WS_TS + BB*TT)
#define WS_NIB    (WS_ATTN + BB*TT)            // bf16 ni 64x1024
#define WS_A1     (WS_NIB + BB*H4/2)           // bf16 [s|ctx] 64x1024
#define WS_AX0    (WS_A1 + BB*H4/2)            // bf16 emb 64x128
#define WS_AH0    (WS_AX0 + BB*EE/2)           // bf16 h_prev0 64x512
#define WS_AH1    (WS_AH0 + BB*HH/2)           // bf16 h_prev1 64x512
#define WS_AX1    (WS_AH1 + BB*HH/2)           // bf16 h0 64x512
#define WS_PGEN   (WS_AX1 + BB*HH/2)
#define WS_RM     (WS_PGEN + 64)
#define WS_RS     (WS_RM + 64)
#define WS_CTXP   (WS_RS + 64)                 // f32 partial ctx 64x8x512 (1 MB)
#define WS_LOGITS (WS_CTXP + BB*NCH*HH)        // f32 64x50000

typedef __attribute__((ext_vector_type(8))) short short8v;
typedef __attribute__((ext_vector_type(4))) short short4v;
typedef __attribute__((ext_vector_type(4))) float f32x4;

__device__ __forceinline__ float wredsum(float v) {
#pragma unroll
  for (int o = 32; o > 0; o >>= 1) v += __shfl_down(v, o, 64);
  return v;
}
__device__ __forceinline__ float wredmax(float v) {
#pragma unroll
  for (int o = 32; o > 0; o >>= 1) v = fmaxf(v, __shfl_down(v, o, 64));
  return v;
}
__device__ __forceinline__ float dot4(float4 a, float4 b) {
  return a.x*b.x + a.y*b.y + a.z*b.z + a.w*b.w;
}
__device__ __forceinline__ float sigmoidf(float x) { return 1.f / (1.f + expf(-x)); }
__device__ __forceinline__ short bfh(float f) {
  union { __hip_bfloat16 h; short s; } u; u.h = __float2bfloat16(f); return u.s;
}

// ---------------- zero copy_prob + loss, and bf16 prep for GRU A-operands ----------------
__global__ void zero_prep_kernel(float* __restrict__ p, float* __restrict__ loss,
                                 const float* __restrict__ embt, const int* __restrict__ ids,
                                 const float* __restrict__ preh,
                                 short* __restrict__ ax0, short* __restrict__ ah0,
                                 short* __restrict__ ah1) {
  int i = blockIdx.x * 256 + threadIdx.x;   // 800000 float4s
  ((float4*)p)[i] = make_float4(0.f, 0.f, 0.f, 0.f);
  if (i == 0) loss[0] = 0.f;
  if (i < BB * EE) {
    int b = i >> 7, k = i & 127;
    ax0[i] = bfh(embt[(size_t)ids[b] * EE + k]);
  } else if (i < BB * EE + 2 * BB * HH) {
    int j = i - BB * EE;
    if (j < BB * HH) ah0[j] = bfh(preh[j]);
    else ah1[j - BB * HH] = bfh(preh[j]);
  }
}

// ---------------- GRU layer via MFMA ----------------
// 128 blocks = 32 col-frags x 4 batch-groups; 6 waves = {r,z,n} x {ih,hh}.
template<int KX>
__global__ __launch_bounds__(384) void gru_mfma_kernel(
    const short* __restrict__ Ax, const short* __restrict__ Ah,
    const float* __restrict__ W_ih, const float* __restrict__ W_hh,
    const float* __restrict__ b_ih, const float* __restrict__ b_hh,
    const float* __restrict__ hprev,
    float* __restrict__ hout_f, float* __restrict__ hout_o,
    short* __restrict__ hout_b, int bstride) {
  __shared__ float P[2][3][16][16];
  const int w = threadIdx.x >> 6;             // 0..5
  const int lane = threadIdx.x & 63;
  const int r16 = lane & 15, kg = lane >> 4;
  const int j0 = (blockIdx.x & 31) * 16;      // gate-col fragment
  const int bg = blockIdx.x >> 5;             // batch group (16 rows)
  const int part = (w >= 3) ? 1 : 0;          // 0 = ih, 1 = hh
  const int g = w - part * 3;                 // gate r/z/n
  const int K = part ? HH : KX;
  const float* Wm = part ? W_hh : W_ih;
  const short* Am = part ? Ah : Ax;

  f32x4 acc = {0.f, 0.f, 0.f, 0.f};
  const float* wp = Wm + (size_t)(g * HH + j0 + r16) * K + kg * 8;
  const short* ap = Am + (size_t)(bg * 16 + r16) * K + kg * 8;
#pragma unroll 4
  for (int k0 = 0; k0 < K; k0 += 32) {
    float4 w0 = *(const float4*)(wp + k0);
    float4 w1 = *(const float4*)(wp + k0 + 4);
    short8v a = *(const short8v*)(ap + k0);
    short8v bf;
    bf[0] = bfh(w0.x); bf[1] = bfh(w0.y); bf[2] = bfh(w0.z); bf[3] = bfh(w0.w);
    bf[4] = bfh(w1.x); bf[5] = bfh(w1.y); bf[6] = bfh(w1.z); bf[7] = bfh(w1.w);
    acc = __builtin_amdgcn_mfma_f32_16x16x32_bf16(a, bf, acc, 0, 0, 0);
  }
#pragma unroll
  for (int r = 0; r < 4; r++) P[part][g][kg * 4 + r][r16] = acc[r];
  __syncthreads();
  if (w == 0) {
    int col = j0 + r16;
    float bir = b_ih[col] + b_hh[col];
    float biz = b_ih[HH + col] + b_hh[HH + col];
    float bin = b_ih[2 * HH + col], bhn = b_hh[2 * HH + col];
#pragma unroll
    for (int r = 0; r < 4; r++) {
      int m = kg * 4 + r;
      int row = bg * 16 + m;
      float rv = sigmoidf(P[0][0][m][r16] + P[1][0][m][r16] + bir);
      float zv = sigmoidf(P[0][1][m][r16] + P[1][1][m][r16] + biz);
      float nv = tanhf(P[0][2][m][r16] + bin + rv * (P[1][2][m][r16] + bhn));
      float h = (1.f - zv) * nv + zv * hprev[(size_t)row * HH + col];
      hout_f[(size_t)row * HH + col] = h;
      hout_o[(size_t)row * HH + col] = h;
      hout_b[(size_t)row * bstride + col] = bfh(h);
    }
  }
}

// ---------------- tanh(scores): one wave per (b,t); sdot/cc fused in ----------------
__global__ void scores_kernel(const float* __restrict__ enc, const float* __restrict__ cov,
                              const float* __restrict__ aW, const float* __restrict__ ab,
                              const float* __restrict__ covW, const float* __restrict__ covb,
                              const float* __restrict__ s, float* __restrict__ ts) {
  int b = blockIdx.y;
  int wid = threadIdx.x >> 6, lane = threadIdx.x & 63;
  int t = blockIdx.x * 4 + wid;
  int i8 = lane * 8;
  const float* e = enc + ((size_t)b * TT + t) * HH + i8;
  float4 a0 = *(const float4*)&aW[i8],        a1 = *(const float4*)&aW[i8 + 4];
  float4 b0 = *(const float4*)&aW[HH + i8],   b1 = *(const float4*)&aW[HH + i8 + 4];
  float4 c0 = *(const float4*)&aW[2*HH + i8], c1 = *(const float4*)&aW[2*HH + i8 + 4];
  float4 s0 = *(const float4*)&s[(size_t)b * HH + i8], s1 = *(const float4*)&s[(size_t)b * HH + i8 + 4];
  float4 w0 = *(const float4*)&covW[i8],      w1 = *(const float4*)&covW[i8 + 4];
  float4 v0 = *(const float4*)&covb[i8],      v1 = *(const float4*)&covb[i8 + 4];
  float covbt = cov[b * TT + t];
  float p1 = dot4(*(const float4*)&e[0], a0) + dot4(*(const float4*)&e[4], a1)
           + dot4(s0, b0) + dot4(s1, b1)
           + dot4(v0, c0) + dot4(v1, c1);
  float p2 = dot4(w0, c0) + dot4(w1, c1);
  float d = wredsum(p1 + covbt * p2);
  if (lane == 0) ts[b * TT + t] = tanhf(d + ab[0]);
}

// ---------------- attention softmax over T + new_coverage + scatter + loss ----------------
__global__ void attn_kernel(const float* __restrict__ ts, const float* __restrict__ cov,
                            const int* __restrict__ src,
                            float* __restrict__ wattn, float* __restrict__ dout,
                            float* __restrict__ outc) {
  int b = blockIdx.x, tid = threadIdx.x;
  int lane = tid & 63, wid = tid >> 6;
  __shared__ float sred[8];
  __shared__ float bval[2];
  float v = (tid < TT) ? ts[b * TT + tid] : -1e30f;
  float wm = wredmax(v);
  if (lane == 0) sred[wid] = wm;
  __syncthreads();
  if (wid == 0) {
    float r = (lane < 8) ? sred[lane] : -1e30f;
    r = wredmax(r);
    if (lane == 0) bval[0] = r;
  }
  __syncthreads();
  float m = bval[0];
  float e = (tid < TT) ? expf(v - m) : 0.f;
  float wsm = wredsum(e);
  __syncthreads();
  if (lane == 0) sred[wid] = wsm;
  __syncthreads();
  if (wid == 0) {
    float r = (lane < 8) ? sred[lane] : 0.f;
    r = wredsum(r);
    if (lane == 0) bval[1] = r;
  }
  __syncthreads();
  float denom = bval[1];
  float a = e / denom;
  float lp = 0.f;
  if (tid < TT) {
    wattn[b * TT + tid] = a;
    dout[OFF_ATTN + b * TT + tid] = a;
    float c = cov[b * TT + tid];
    dout[OFF_NEWCOV + b * TT + tid] = c + a;
    lp = fminf(a, c);
    atomicAdd(&outc[(size_t)b * VV + src[b * TT + tid]], a);
  }
  float wl = wredsum(lp);
  __syncthreads();
  if (lane == 0) sred[wid] = wl;
  __syncthreads();
  if (wid == 0) {
    float r = (lane < 8) ? sred[lane] : 0.f;
    r = wredsum(r);
    if (lane == 0) atomicAdd(&dout[OFF_LOSS], r);
  }
}

// ---------------- ctx partials: grid (b, chunk); 512 threads ----------------
__global__ void ctx_part_kernel(const float* __restrict__ enc, const float* __restrict__ attn,
                                float* __restrict__ ctxp) {
  int b = blockIdx.x, c = blockIdx.y;
  int h = threadIdx.x;
  __shared__ float as[TT / NCH];
  if (h < TT / NCH) as[h] = attn[b * TT + c * (TT / NCH) + h];
  __syncthreads();
  const float* e = enc + ((size_t)b * TT + c * (TT / NCH)) * HH + h;
  float acc = 0.f;
#pragma unroll 10
  for (int t = 0; t < TT / NCH; t++) acc += as[t] * e[(size_t)t * HH];
  ctxp[((size_t)b * NCH + c) * HH + h] = acc;
}

// ---------------- ctx reduce + bf16 into A1 + p_gen ----------------
__global__ void ctxred_pgen_kernel(const float* __restrict__ ctxp, const float* __restrict__ s,
                                   const float* __restrict__ embt, const int* __restrict__ ids,
                                   const float* __restrict__ gW, const float* __restrict__ gb,
                                   short* __restrict__ a1, float* __restrict__ pgen) {
  int b = blockIdx.x, tid = threadIdx.x;     // 512 threads
  int lane = tid & 63, wid = tid >> 6;
  __shared__ float sred[8];
  float acc = 0.f;
#pragma unroll
  for (int c = 0; c < NCH; c++) acc += ctxp[((size_t)b * NCH + c) * HH + tid];
  a1[(size_t)b * H4 + HH + tid] = bfh(acc);
  float part = acc * gW[tid] + s[b * HH + tid] * gW[HH + tid];
  if (tid < EE) part += embt[(size_t)ids[b] * EE + tid] * gW[2 * HH + tid];
  float w = wredsum(part);
  if (lane == 0) sred[wid] = w;
  __syncthreads();
  if (wid == 0) {
    float r = (lane < 8) ? sred[lane] : 0.f;
    r = wredsum(r);
    if (lane == 0) pgen[b] = sigmoidf(r + gb[0]);
  }
}

// ---------------- fc1 via MFMA, K-split 4: ni = tanh(A1 @ W^T + b) -> bf16 ----------------
__global__ __launch_bounds__(256) void fc1_kernel(const short* __restrict__ a1,
                                                  const float* __restrict__ W,
                                                  const float* __restrict__ bias,
                                                  short* __restrict__ nib) {
  __shared__ float part[4096];
  const int w = threadIdx.x >> 6;
  const int lane = threadIdx.x & 63;
  const int r16 = lane & 15, kg = lane >> 4;
  const int v0 = blockIdx.x * 16;
  const int kb = w * 256;

  f32x4 acc0 = {0.f,0.f,0.f,0.f}, acc1 = {0.f,0.f,0.f,0.f};
  f32x4 acc2 = {0.f,0.f,0.f,0.f}, acc3 = {0.f,0.f,0.f,0.f};
  const float* wp = W + (size_t)(v0 + r16) * H4 + kb + kg * 8;
  const short* ap = a1 + (size_t)r16 * H4 + kb + kg * 8;
#pragma unroll 4
  for (int k0 = 0; k0 < 256; k0 += 32) {
    float4 w0 = *(const float4*)(wp + k0);
    float4 w1 = *(const float4*)(wp + k0 + 4);
    short8v a0 = *(const short8v*)(ap + k0);
    short8v a1v = *(const short8v*)(ap + 16 * H4 + k0);
    short8v a2 = *(const short8v*)(ap + 32 * H4 + k0);
    short8v a3 = *(const short8v*)(ap + 48 * H4 + k0);
    short8v bf;
    bf[0] = bfh(w0.x); bf[1] = bfh(w0.y); bf[2] = bfh(w0.z); bf[3] = bfh(w0.w);
    bf[4] = bfh(w1.x); bf[5] = bfh(w1.y); bf[6] = bfh(w1.z); bf[7] = bfh(w1.w);
    acc0 = __builtin_amdgcn_mfma_f32_16x16x32_bf16(a0, bf, acc0, 0, 0, 0);
    acc1 = __builtin_amdgcn_mfma_f32_16x16x32_bf16(a1v, bf, acc1, 0, 0, 0);
    acc2 = __builtin_amdgcn_mfma_f32_16x16x32_bf16(a2, bf, acc2, 0, 0, 0);
    acc3 = __builtin_amdgcn_mfma_f32_16x16x32_bf16(a3, bf, acc3, 0, 0, 0);
  }
  float* pb = part + w * 1024;
#pragma unroll
  for (int r = 0; r < 4; r++) {
    pb[(kg * 4 + r) * 16 + r16]      = acc0[r];
    pb[(16 + kg * 4 + r) * 16 + r16] = acc1[r];
    pb[(32 + kg * 4 + r) * 16 + r16] = acc2[r];
    pb[(48 + kg * 4 + r) * 16 + r16] = acc3[r];
  }
  __syncthreads();
  int idx = threadIdx.x * 4;
  int m = idx >> 4, c0 = idx & 15;
  f32x4 s0 = *(const f32x4*)(part + idx);
  f32x4 s1 = *(const f32x4*)(part + 1024 + idx);
  f32x4 s2 = *(const f32x4*)(part + 2048 + idx);
  f32x4 s3 = *(const f32x4*)(part + 3072 + idx);
  f32x4 bv = *(const f32x4*)(bias + v0 + c0);
  f32x4 o = s0 + s1 + s2 + s3 + bv;
#pragma unroll
  for (int j = 0; j < 4; j++)
    nib[(size_t)m * H4 + v0 + c0 + j] = bfh(tanhf(o[j]));
}

// ---------------- fc2 v4: LDS-staged MFMA GEMM, tile 64M x 64N, BK=128 ----------------
// 35 KB LDS -> 4 blocks/CU resident; 782 blocks fit one scheduling pass.
// Staging fully coalesced (16 rows x 64B full sectors per instruction).
__global__ __launch_bounds__(256) void fc2_kernel(const short* __restrict__ nib,
                                                  const float* __restrict__ W,
                                                  const float* __restrict__ bias,
                                                  float* __restrict__ logits) {
  __shared__ short Wl[64 * LSTR];   // 17.4 KB
  __shared__ short Al[64 * LSTR];   // 17.4 KB
  const int tid = threadIdx.x;
  const int w = tid >> 6, lane = tid & 63;
  const int r16 = lane & 15, kg = lane >> 4;
  const int v0 = blockIdx.x * 64;
  const int srow = tid >> 2, quad = tid & 3;          // staging role
  const int vr = min(v0 + srow, VV - 1);              // clamp OOB vocab rows

  f32x4 acc[4];
#pragma unroll
  for (int i = 0; i < 4; i++) acc[i] = (f32x4){0.f, 0.f, 0.f, 0.f};

  for (int k0 = 0; k0 < H4; k0 += 128) {
    __syncthreads();
    // ---- stage W tile [64v][128k] f32 -> bf16 LDS ----
    {
      const float* src = W + (size_t)vr * H4 + k0 + quad * 4;
      char* dst = (char*)Wl + srow * (LSTR * 2) + quad * 8;
#pragma unroll
      for (int j = 0; j < 8; j++) {
        float4 f = *(const float4*)(src + j * 16);
        short4v h; h[0] = bfh(f.x); h[1] = bfh(f.y); h[2] = bfh(f.z); h[3] = bfh(f.w);
        *(short4v*)(dst + j * 32) = h;
      }
      // ---- stage A tile [64m][128k] bf16 (straight copy) ----
      const short* asrc = nib + (size_t)srow * H4 + k0 + quad * 8;
      char* adst = (char*)Al + srow * (LSTR * 2) + quad * 16;
#pragma unroll
      for (int j = 0; j < 4; j++)
        *(short8v*)(adst + j * 64) = *(const short8v*)(asrc + j * 32);
    }
    __syncthreads();
    // ---- compute: 4 sub-k of 32; wave w owns 16 vocab cols ----
#pragma unroll
    for (int s = 0; s < 4; s++) {
      short8v wf = *(const short8v*)((char*)Wl + (w * 16 + r16) * (LSTR * 2) + s * 64 + kg * 16);
#pragma unroll
      for (int i = 0; i < 4; i++) {
        short8v af = *(const short8v*)((char*)Al + (i * 16 + r16) * (LSTR * 2) + s * 64 + kg * 16);
        acc[i] = __builtin_amdgcn_mfma_f32_16x16x32_bf16(af, wf, acc[i], 0, 0, 0);
      }
    }
  }

  // ---- epilogue: transpose through LDS, coalesced float4 stores ----
  __syncthreads();
  float* sc = (float*)Wl;                             // 16 KB scratch (fits 17.4 KB)
#pragma unroll
  for (int i = 0; i < 4; i++)
#pragma unroll
    for (int r = 0; r < 4; r++)
      sc[(i * 16 + kg * 4 + r) * 64 + w * 16 + r16] = acc[i][r];
  __syncthreads();
  int m = tid >> 2, c = (tid & 3) * 16;
  const float* scp = sc + m * 64 + c;
#pragma unroll
  for (int j = 0; j < 4; j++) {
    int col = v0 + c + j * 4;
    if (col < VV) {
      float4 s = *(const float4*)(scp + j * 4);
      float4 bv = *(const float4*)(bias + col);
      *(float4*)(logits + (size_t)m * VV + col) =
          make_float4(s.x + bv.x, s.y + bv.y, s.z + bv.z, s.w + bv.w);
    }
  }
}

// ---------------- per-row vocab softmax stats ----------------
__global__ void smax_kernel(const float* __restrict__ logits, float* __restrict__ rm,
                            float* __restrict__ rs) {
  int b = blockIdx.x, tid = threadIdx.x;
  int lane = tid & 63, wid = tid >> 6;
  __shared__ float sred[4];
  __shared__ float bval[2];
  const float4* row = (const float4*)(logits + (size_t)b * VV);
  float m = -1e30f;
  for (int i = tid; i < VV / 4; i += 256) {
    float4 l = row[i];
    m = fmaxf(m, fmaxf(fmaxf(l.x, l.y), fmaxf(l.z, l.w)));
  }
  m = wredmax(m);
  if (lane == 0) sred[wid] = m;
  __syncthreads();
  if (wid == 0) {
    float r = (lane < 4) ? sred[lane] : -1e30f;
    r = wredmax(r);
    if (lane == 0) bval[0] = r;
  }
  __syncthreads();
  float bm = bval[0];
  float sacc = 0.f;
  for (int i = tid; i < VV / 4; i += 256) {
    float4 l = row[i];
    sacc += expf(l.x - bm) + expf(l.y - bm) + expf(l.z - bm) + expf(l.w - bm);
  }
  sacc = wredsum(sacc);
  __syncthreads();
  if (lane == 0) sred[wid] = sacc;
  __syncthreads();
  if (wid == 0) {
    float r = (lane < 4) ? sred[lane] : 0.f;
    r = wredsum(r);
    if (lane == 0) { rm[b] = bm; rs[b] = r; }
  }
}

// ---------------- final mix: out = Pvocab*p_gen + copy*(1-p_gen) ----------------
__global__ void final_kernel(const float* __restrict__ logits, const float* __restrict__ rm,
                             const float* __restrict__ rs, const float* __restrict__ pgen,
                             const float* __restrict__ copy, float* __restrict__ out) {
  int i = blockIdx.x * 256 + threadIdx.x;     // over 800000 float4s
  int b = (i * 4) / VV;
  float p = pgen[b], m = rm[b], s = rs[b];
  float4 l = ((const float4*)logits)[i];
  float4 c = ((const float4*)copy)[i];
  float q = 1.f - p;
  float4 o;
  o.x = expf(l.x - m) / s * p + c.x * q;
  o.y = expf(l.y - m) / s * p + c.y * q;
  o.z = expf(l.z - m) / s * p + c.z * q;
  o.w = expf(l.w - m) / s * p + c.w * q;
  ((float4*)out)[i] = o;
}

extern "C" void kernel_launch(void* const* d_in, const int* in_sizes, int n_in,
                              void* d_out, int out_size, void* d_ws, size_t ws_size,
                              hipStream_t stream) {
  const int*   ids  = (const int*)d_in[0];
  const float* preh = (const float*)d_in[1];
  const float* enc  = (const float*)d_in[2];
  const int*   src  = (const int*)d_in[3];
  const float* cov  = (const float*)d_in[4];
  const float* embt = (const float*)d_in[5];
  const float* Wih0 = (const float*)d_in[6];
  const float* Whh0 = (const float*)d_in[7];
  const float* bih0 = (const float*)d_in[8];
  const float* bhh0 = (const float*)d_in[9];
  const float* Wih1 = (const float*)d_in[10];
  const float* Whh1 = (const float*)d_in[11];
  const float* bih1 = (const float*)d_in[12];
  const float* bhh1 = (const float*)d_in[13];
  const float* aW   = (const float*)d_in[14];
  const float* ab   = (const float*)d_in[15];
  const float* covW = (const float*)d_in[16];
  const float* covb = (const float*)d_in[17];
  const float* f1W  = (const float*)d_in[18];
  const float* f1b  = (const float*)d_in[19];
  const float* f2W  = (const float*)d_in[20];
  const float* f2b  = (const float*)d_in[21];
  const float* gW   = (const float*)d_in[22];
  const float* gb   = (const float*)d_in[23];
  float* out = (float*)d_out;
  float* ws  = (float*)d_ws;

  zero_prep_kernel<<<3125, 256, 0, stream>>>(out + OFF_COPY, out + OFF_LOSS,
                                             embt, ids, preh,
                                             (short*)(ws + WS_AX0), (short*)(ws + WS_AH0),
                                             (short*)(ws + WS_AH1));
  gru_mfma_kernel<EE><<<128, 384, 0, stream>>>(
      (const short*)(ws + WS_AX0), (const short*)(ws + WS_AH0),
      Wih0, Whh0, bih0, bhh0, preh,
      out + OFF_CURHID, out + OFF_CURHID, (short*)(ws + WS_AX1), HH);
  gru_mfma_kernel<HH><<<128, 384, 0, stream>>>(
      (const short*)(ws + WS_AX1), (const short*)(ws + WS_AH1),
      Wih1, Whh1, bih1, bhh1, preh + BB * HH,
      ws + WS_S, out + OFF_CURHID + BB * HH, (short*)(ws + WS_A1), H4);
  scores_kernel<<<dim3(100, 64), 256, 0, stream>>>(enc, cov, aW, ab, covW, covb,
                                                   ws + WS_S, ws + WS_TS);
  attn_kernel<<<64, 512, 0, stream>>>(ws + WS_TS, cov, src, ws + WS_ATTN, out,
                                      out + OFF_COPY);
  ctx_part_kernel<<<dim3(64, NCH), 512, 0, stream>>>(enc, ws + WS_ATTN, ws + WS_CTXP);
  ctxred_pgen_kernel<<<64, 512, 0, stream>>>(ws + WS_CTXP, ws + WS_S, embt, ids, gW, gb,
                                             (short*)(ws + WS_A1), ws + WS_PGEN);
  fc1_kernel<<<64, 256, 0, stream>>>((const short*)(ws + WS_A1), f1W, f1b,
                                     (short*)(ws + WS_NIB));
  fc2_kernel<<<782, 256, 0, stream>>>((const short*)(ws + WS_NIB), f2W, f2b,
                                      ws + WS_LOGITS);
  smax_kernel<<<64, 256, 0, stream>>>(ws + WS_LOGITS, ws + WS_RM, ws + WS_RS);
  final_kernel<<<3125, 256, 0, stream>>>(ws + WS_LOGITS, ws + WS_RM, ws + WS_RS,
                                         ws + WS_PGEN, out + OFF_COPY, out);
}

// Round 8
// 130.207 us; speedup vs baseline: 4.3576x; 1.1774x over previous
//
#include <hip/hip_runtime.h>
#include <hip/hip_bf16.h>
#include <cstddef>

#define BB 64
#define TT 400
#define EE 128
#define HH 512
#define H4 1024
#define VV 50000
#define NCH 8                                  // ctx T-chunks
#define LSTR 136                               // fc2 LDS row stride in shorts (128+8 pad)

// ---- d_out layout (floats), reference return order ----
#define OFF_OUT     0
#define OFF_CURHID  (BB*VV)                    // 3,200,000
#define OFF_ATTN    (OFF_CURHID + 2*BB*HH)     // 3,265,536
#define OFF_COPY    (OFF_ATTN + BB*TT)         // 3,291,136
#define OFF_NEWCOV  (OFF_COPY + BB*VV)         // 6,491,136
#define OFF_LOSS    (OFF_NEWCOV + BB*TT)       // 6,516,736

// ---- workspace layout (floats; bf16 buffers noted) ----
#define WS_S      0                            // f32 s 64x512
#define WS_TS     (WS_S + BB*HH)
#define WS_ATTN   (WS_TS + BB*TT)
#define WS_NIB    (WS_ATTN + BB*TT)            // bf16 ni 64x1024
#define WS_A1     (WS_NIB + BB*H4/2)           // bf16 [s|ctx] 64x1024
#define WS_AX0    (WS_A1 + BB*H4/2)            // bf16 emb 64x128
#define WS_AH0    (WS_AX0 + BB*EE/2)           // bf16 h_prev0 64x512
#define WS_AH1    (WS_AH0 + BB*HH/2)           // bf16 h_prev1 64x512
#define WS_AX1    (WS_AH1 + BB*HH/2)           // bf16 h0 64x512
#define WS_PGEN   (WS_AX1 + BB*HH/2)
#define WS_RM     (WS_PGEN + 64)
#define WS_RS     (WS_RM + 64)
#define WS_CTXP   (WS_RS + 64)                 // f32 partial ctx 64x8x512 (1 MB)
#define WS_LOGITS (WS_CTXP + BB*NCH*HH)        // bf16 64x50000 (1.6M floats used)

typedef __attribute__((ext_vector_type(8))) short short8v;
typedef __attribute__((ext_vector_type(4))) short short4v;
typedef __attribute__((ext_vector_type(4))) float f32x4;

__device__ __forceinline__ float wredsum(float v) {
#pragma unroll
  for (int o = 32; o > 0; o >>= 1) v += __shfl_down(v, o, 64);
  return v;
}
__device__ __forceinline__ float wredmax(float v) {
#pragma unroll
  for (int o = 32; o > 0; o >>= 1) v = fmaxf(v, __shfl_down(v, o, 64));
  return v;
}
__device__ __forceinline__ float dot4(float4 a, float4 b) {
  return a.x*b.x + a.y*b.y + a.z*b.z + a.w*b.w;
}
__device__ __forceinline__ float sigmoidf(float x) { return 1.f / (1.f + expf(-x)); }
__device__ __forceinline__ short bfh(float f) {
  union { __hip_bfloat16 h; short s; } u; u.h = __float2bfloat16(f); return u.s;
}
__device__ __forceinline__ float bf2f(short s) {
  union { unsigned int u; float f; } v; v.u = ((unsigned int)(unsigned short)s) << 16; return v.f;
}

// ---------------- zero copy_prob + loss + rs, and bf16 prep for GRU A-operands ----------------
__global__ void zero_prep_kernel(float* __restrict__ p, float* __restrict__ loss,
                                 float* __restrict__ rs,
                                 const float* __restrict__ embt, const int* __restrict__ ids,
                                 const float* __restrict__ preh,
                                 short* __restrict__ ax0, short* __restrict__ ah0,
                                 short* __restrict__ ah1) {
  int i = blockIdx.x * 256 + threadIdx.x;   // 800000 float4s
  ((float4*)p)[i] = make_float4(0.f, 0.f, 0.f, 0.f);
  if (i == 0) loss[0] = 0.f;
  if (i < 64) rs[i] = 0.f;
  if (i < BB * EE) {
    int b = i >> 7, k = i & 127;
    ax0[i] = bfh(embt[(size_t)ids[b] * EE + k]);
  } else if (i < BB * EE + 2 * BB * HH) {
    int j = i - BB * EE;
    if (j < BB * HH) ah0[j] = bfh(preh[j]);
    else ah1[j - BB * HH] = bfh(preh[j]);
  }
}

// ---------------- GRU layer via MFMA ----------------
// 128 blocks = 32 col-frags x 4 batch-groups; 6 waves = {r,z,n} x {ih,hh}.
template<int KX>
__global__ __launch_bounds__(384) void gru_mfma_kernel(
    const short* __restrict__ Ax, const short* __restrict__ Ah,
    const float* __restrict__ W_ih, const float* __restrict__ W_hh,
    const float* __restrict__ b_ih, const float* __restrict__ b_hh,
    const float* __restrict__ hprev,
    float* __restrict__ hout_f, float* __restrict__ hout_o,
    short* __restrict__ hout_b, int bstride) {
  __shared__ float P[2][3][16][16];
  const int w = threadIdx.x >> 6;             // 0..5
  const int lane = threadIdx.x & 63;
  const int r16 = lane & 15, kg = lane >> 4;
  const int j0 = (blockIdx.x & 31) * 16;      // gate-col fragment
  const int bg = blockIdx.x >> 5;             // batch group (16 rows)
  const int part = (w >= 3) ? 1 : 0;          // 0 = ih, 1 = hh
  const int g = w - part * 3;                 // gate r/z/n
  const int K = part ? HH : KX;
  const float* Wm = part ? W_hh : W_ih;
  const short* Am = part ? Ah : Ax;

  f32x4 acc = {0.f, 0.f, 0.f, 0.f};
  const float* wp = Wm + (size_t)(g * HH + j0 + r16) * K + kg * 8;
  const short* ap = Am + (size_t)(bg * 16 + r16) * K + kg * 8;
#pragma unroll 4
  for (int k0 = 0; k0 < K; k0 += 32) {
    float4 w0 = *(const float4*)(wp + k0);
    float4 w1 = *(const float4*)(wp + k0 + 4);
    short8v a = *(const short8v*)(ap + k0);
    short8v bf;
    bf[0] = bfh(w0.x); bf[1] = bfh(w0.y); bf[2] = bfh(w0.z); bf[3] = bfh(w0.w);
    bf[4] = bfh(w1.x); bf[5] = bfh(w1.y); bf[6] = bfh(w1.z); bf[7] = bfh(w1.w);
    acc = __builtin_amdgcn_mfma_f32_16x16x32_bf16(a, bf, acc, 0, 0, 0);
  }
#pragma unroll
  for (int r = 0; r < 4; r++) P[part][g][kg * 4 + r][r16] = acc[r];
  __syncthreads();
  if (w == 0) {
    int col = j0 + r16;
    float bir = b_ih[col] + b_hh[col];
    float biz = b_ih[HH + col] + b_hh[HH + col];
    float bin = b_ih[2 * HH + col], bhn = b_hh[2 * HH + col];
#pragma unroll
    for (int r = 0; r < 4; r++) {
      int m = kg * 4 + r;
      int row = bg * 16 + m;
      float rv = sigmoidf(P[0][0][m][r16] + P[1][0][m][r16] + bir);
      float zv = sigmoidf(P[0][1][m][r16] + P[1][1][m][r16] + biz);
      float nv = tanhf(P[0][2][m][r16] + bin + rv * (P[1][2][m][r16] + bhn));
      float h = (1.f - zv) * nv + zv * hprev[(size_t)row * HH + col];
      hout_f[(size_t)row * HH + col] = h;
      hout_o[(size_t)row * HH + col] = h;
      hout_b[(size_t)row * bstride + col] = bfh(h);
    }
  }
}

// ---------------- tanh(scores): one wave per (b,t); sdot/cc fused in ----------------
__global__ void scores_kernel(const float* __restrict__ enc, const float* __restrict__ cov,
                              const float* __restrict__ aW, const float* __restrict__ ab,
                              const float* __restrict__ covW, const float* __restrict__ covb,
                              const float* __restrict__ s, float* __restrict__ ts) {
  int b = blockIdx.y;
  int wid = threadIdx.x >> 6, lane = threadIdx.x & 63;
  int t = blockIdx.x * 4 + wid;
  int i8 = lane * 8;
  const float* e = enc + ((size_t)b * TT + t) * HH + i8;
  float4 a0 = *(const float4*)&aW[i8],        a1 = *(const float4*)&aW[i8 + 4];
  float4 b0 = *(const float4*)&aW[HH + i8],   b1 = *(const float4*)&aW[HH + i8 + 4];
  float4 c0 = *(const float4*)&aW[2*HH + i8], c1 = *(const float4*)&aW[2*HH + i8 + 4];
  float4 s0 = *(const float4*)&s[(size_t)b * HH + i8], s1 = *(const float4*)&s[(size_t)b * HH + i8 + 4];
  float4 w0 = *(const float4*)&covW[i8],      w1 = *(const float4*)&covW[i8 + 4];
  float4 v0 = *(const float4*)&covb[i8],      v1 = *(const float4*)&covb[i8 + 4];
  float covbt = cov[b * TT + t];
  float p1 = dot4(*(const float4*)&e[0], a0) + dot4(*(const float4*)&e[4], a1)
           + dot4(s0, b0) + dot4(s1, b1)
           + dot4(v0, c0) + dot4(v1, c1);
  float p2 = dot4(w0, c0) + dot4(w1, c1);
  float d = wredsum(p1 + covbt * p2);
  if (lane == 0) ts[b * TT + t] = tanhf(d + ab[0]);
}

// ---------------- attention softmax over T + new_coverage + scatter + loss ----------------
__global__ void attn_kernel(const float* __restrict__ ts, const float* __restrict__ cov,
                            const int* __restrict__ src,
                            float* __restrict__ wattn, float* __restrict__ dout,
                            float* __restrict__ outc) {
  int b = blockIdx.x, tid = threadIdx.x;
  int lane = tid & 63, wid = tid >> 6;
  __shared__ float sred[8];
  __shared__ float bval[2];
  float v = (tid < TT) ? ts[b * TT + tid] : -1e30f;
  float wm = wredmax(v);
  if (lane == 0) sred[wid] = wm;
  __syncthreads();
  if (wid == 0) {
    float r = (lane < 8) ? sred[lane] : -1e30f;
    r = wredmax(r);
    if (lane == 0) bval[0] = r;
  }
  __syncthreads();
  float m = bval[0];
  float e = (tid < TT) ? expf(v - m) : 0.f;
  float wsm = wredsum(e);
  __syncthreads();
  if (lane == 0) sred[wid] = wsm;
  __syncthreads();
  if (wid == 0) {
    float r = (lane < 8) ? sred[lane] : 0.f;
    r = wredsum(r);
    if (lane == 0) bval[1] = r;
  }
  __syncthreads();
  float denom = bval[1];
  float a = e / denom;
  float lp = 0.f;
  if (tid < TT) {
    wattn[b * TT + tid] = a;
    dout[OFF_ATTN + b * TT + tid] = a;
    float c = cov[b * TT + tid];
    dout[OFF_NEWCOV + b * TT + tid] = c + a;
    lp = fminf(a, c);
    atomicAdd(&outc[(size_t)b * VV + src[b * TT + tid]], a);
  }
  float wl = wredsum(lp);
  __syncthreads();
  if (lane == 0) sred[wid] = wl;
  __syncthreads();
  if (wid == 0) {
    float r = (lane < 8) ? sred[lane] : 0.f;
    r = wredsum(r);
    if (lane == 0) atomicAdd(&dout[OFF_LOSS], r);
  }
}

// ---------------- ctx partials: grid (b, chunk); 512 threads ----------------
__global__ void ctx_part_kernel(const float* __restrict__ enc, const float* __restrict__ attn,
                                float* __restrict__ ctxp) {
  int b = blockIdx.x, c = blockIdx.y;
  int h = threadIdx.x;
  __shared__ float as[TT / NCH];
  if (h < TT / NCH) as[h] = attn[b * TT + c * (TT / NCH) + h];
  __syncthreads();
  const float* e = enc + ((size_t)b * TT + c * (TT / NCH)) * HH + h;
  float acc = 0.f;
#pragma unroll 10
  for (int t = 0; t < TT / NCH; t++) acc += as[t] * e[(size_t)t * HH];
  ctxp[((size_t)b * NCH + c) * HH + h] = acc;
}

// ---------------- ctx reduce + bf16 into A1 + p_gen ----------------
__global__ void ctxred_pgen_kernel(const float* __restrict__ ctxp, const float* __restrict__ s,
                                   const float* __restrict__ embt, const int* __restrict__ ids,
                                   const float* __restrict__ gW, const float* __restrict__ gb,
                                   short* __restrict__ a1, float* __restrict__ pgen) {
  int b = blockIdx.x, tid = threadIdx.x;     // 512 threads
  int lane = tid & 63, wid = tid >> 6;
  __shared__ float sred[8];
  float acc = 0.f;
#pragma unroll
  for (int c = 0; c < NCH; c++) acc += ctxp[((size_t)b * NCH + c) * HH + tid];
  a1[(size_t)b * H4 + HH + tid] = bfh(acc);
  float part = acc * gW[tid] + s[b * HH + tid] * gW[HH + tid];
  if (tid < EE) part += embt[(size_t)ids[b] * EE + tid] * gW[2 * HH + tid];
  float w = wredsum(part);
  if (lane == 0) sred[wid] = w;
  __syncthreads();
  if (wid == 0) {
    float r = (lane < 8) ? sred[lane] : 0.f;
    r = wredsum(r);
    if (lane == 0) pgen[b] = sigmoidf(r + gb[0]);
  }
}

// ---------------- fc1 via MFMA, K-split 4: ni = tanh(A1 @ W^T + b) -> bf16 ----------------
__global__ __launch_bounds__(256) void fc1_kernel(const short* __restrict__ a1,
                                                  const float* __restrict__ W,
                                                  const float* __restrict__ bias,
                                                  short* __restrict__ nib) {
  __shared__ float part[4096];
  const int w = threadIdx.x >> 6;
  const int lane = threadIdx.x & 63;
  const int r16 = lane & 15, kg = lane >> 4;
  const int v0 = blockIdx.x * 16;
  const int kb = w * 256;

  f32x4 acc0 = {0.f,0.f,0.f,0.f}, acc1 = {0.f,0.f,0.f,0.f};
  f32x4 acc2 = {0.f,0.f,0.f,0.f}, acc3 = {0.f,0.f,0.f,0.f};
  const float* wp = W + (size_t)(v0 + r16) * H4 + kb + kg * 8;
  const short* ap = a1 + (size_t)r16 * H4 + kb + kg * 8;
#pragma unroll 4
  for (int k0 = 0; k0 < 256; k0 += 32) {
    float4 w0 = *(const float4*)(wp + k0);
    float4 w1 = *(const float4*)(wp + k0 + 4);
    short8v a0 = *(const short8v*)(ap + k0);
    short8v a1v = *(const short8v*)(ap + 16 * H4 + k0);
    short8v a2 = *(const short8v*)(ap + 32 * H4 + k0);
    short8v a3 = *(const short8v*)(ap + 48 * H4 + k0);
    short8v bf;
    bf[0] = bfh(w0.x); bf[1] = bfh(w0.y); bf[2] = bfh(w0.z); bf[3] = bfh(w0.w);
    bf[4] = bfh(w1.x); bf[5] = bfh(w1.y); bf[6] = bfh(w1.z); bf[7] = bfh(w1.w);
    acc0 = __builtin_amdgcn_mfma_f32_16x16x32_bf16(a0, bf, acc0, 0, 0, 0);
    acc1 = __builtin_amdgcn_mfma_f32_16x16x32_bf16(a1v, bf, acc1, 0, 0, 0);
    acc2 = __builtin_amdgcn_mfma_f32_16x16x32_bf16(a2, bf, acc2, 0, 0, 0);
    acc3 = __builtin_amdgcn_mfma_f32_16x16x32_bf16(a3, bf, acc3, 0, 0, 0);
  }
  float* pb = part + w * 1024;
#pragma unroll
  for (int r = 0; r < 4; r++) {
    pb[(kg * 4 + r) * 16 + r16]      = acc0[r];
    pb[(16 + kg * 4 + r) * 16 + r16] = acc1[r];
    pb[(32 + kg * 4 + r) * 16 + r16] = acc2[r];
    pb[(48 + kg * 4 + r) * 16 + r16] = acc3[r];
  }
  __syncthreads();
  int idx = threadIdx.x * 4;
  int m = idx >> 4, c0 = idx & 15;
  f32x4 s0 = *(const f32x4*)(part + idx);
  f32x4 s1 = *(const f32x4*)(part + 1024 + idx);
  f32x4 s2 = *(const f32x4*)(part + 2048 + idx);
  f32x4 s3 = *(const f32x4*)(part + 3072 + idx);
  f32x4 bv = *(const f32x4*)(bias + v0 + c0);
  f32x4 o = s0 + s1 + s2 + s3 + bv;
#pragma unroll
  for (int j = 0; j < 4; j++)
    nib[(size_t)m * H4 + v0 + c0 + j] = bfh(tanhf(o[j]));
}

// ---------------- fc2 v5: LDS-staged MFMA GEMM, T14 reg-dbuf, bf16 logits, ----------------
// ---------------- fused exp-partial-sum (softmax denominator via atomics)  ----------------
__global__ __launch_bounds__(256) void fc2_kernel(const short* __restrict__ nib,
                                                  const float* __restrict__ W,
                                                  const float* __restrict__ bias,
                                                  short* __restrict__ logits_bf,
                                                  float* __restrict__ rs) {
  __shared__ short Wl[64 * LSTR];   // 17.4 KB
  __shared__ short Al[64 * LSTR];   // 17.4 KB
  const int tid = threadIdx.x;
  const int w = tid >> 6, lane = tid & 63;
  const int r16 = lane & 15, kg = lane >> 4;
  const int v0 = blockIdx.x * 64;
  const int srow = tid >> 2, quad = tid & 3;          // staging role
  const int vr = min(v0 + srow, VV - 1);              // clamp OOB vocab rows

  f32x4 acc[4];
#pragma unroll
  for (int i = 0; i < 4; i++) acc[i] = (f32x4){0.f, 0.f, 0.f, 0.f};

  const float* wsrc = W + (size_t)vr * H4 + quad * 4;
  const short* asrc = nib + (size_t)srow * H4 + quad * 8;

  // prefetch K-step 0 into registers
  float4 wreg[8];
  short8v areg[4];
#pragma unroll
  for (int j = 0; j < 8; j++) wreg[j] = *(const float4*)(wsrc + j * 16);
#pragma unroll
  for (int j = 0; j < 4; j++) areg[j] = *(const short8v*)(asrc + j * 32);

  for (int ks = 0; ks < 8; ks++) {
    // ---- write staged registers -> LDS (convert W to bf16) ----
    {
      char* dst = (char*)Wl + srow * (LSTR * 2) + quad * 8;
#pragma unroll
      for (int j = 0; j < 8; j++) {
        float4 f = wreg[j];
        short4v h; h[0] = bfh(f.x); h[1] = bfh(f.y); h[2] = bfh(f.z); h[3] = bfh(f.w);
        *(short4v*)(dst + j * 32) = h;
      }
      char* adst = (char*)Al + srow * (LSTR * 2) + quad * 16;
#pragma unroll
      for (int j = 0; j < 4; j++)
        *(short8v*)(adst + j * 64) = areg[j];
    }
    __syncthreads();
    // ---- issue next K-step's loads (in flight across compute + barrier) ----
    if (ks < 7) {
      const float* ws2 = wsrc + (ks + 1) * 128;
      const short* as2 = asrc + (ks + 1) * 128;
#pragma unroll
      for (int j = 0; j < 8; j++) wreg[j] = *(const float4*)(ws2 + j * 16);
#pragma unroll
      for (int j = 0; j < 4; j++) areg[j] = *(const short8v*)(as2 + j * 32);
    }
    // ---- compute: 4 sub-k of 32; wave w owns 16 vocab cols ----
#pragma unroll
    for (int s = 0; s < 4; s++) {
      short8v wf = *(const short8v*)((char*)Wl + (w * 16 + r16) * (LSTR * 2) + s * 64 + kg * 16);
#pragma unroll
      for (int i = 0; i < 4; i++) {
        short8v af = *(const short8v*)((char*)Al + (i * 16 + r16) * (LSTR * 2) + s * 64 + kg * 16);
        acc[i] = __builtin_amdgcn_mfma_f32_16x16x32_bf16(af, wf, acc[i], 0, 0, 0);
      }
    }
    __syncthreads();   // protect LDS before next write phase
  }

  // ---- epilogue: transpose via LDS, bf16 logits + per-row exp partial sums ----
  float* sc = (float*)Wl;                             // 16 KB scratch
#pragma unroll
  for (int i = 0; i < 4; i++)
#pragma unroll
    for (int r = 0; r < 4; r++)
      sc[(i * 16 + kg * 4 + r) * 64 + w * 16 + r16] = acc[i][r];
  __syncthreads();
  int m = tid >> 2, q = tid & 3;
  int colbase = v0 + q * 16;                          // VV%16==0 -> all-or-nothing valid
  float esum = 0.f;
  if (colbase < VV) {
    const float* scp = sc + m * 64 + q * 16;
    short8v lo, hi;
#pragma unroll
    for (int j = 0; j < 8; j++) {
      short lb = bfh(scp[j] + bias[colbase + j]);
      lo[j] = lb;
      esum += expf(bf2f(lb));
    }
#pragma unroll
    for (int j = 0; j < 8; j++) {
      short lb = bfh(scp[8 + j] + bias[colbase + 8 + j]);
      hi[j] = lb;
      esum += expf(bf2f(lb));
    }
    *(short8v*)(logits_bf + (size_t)m * VV + colbase)     = lo;
    *(short8v*)(logits_bf + (size_t)m * VV + colbase + 8) = hi;
  }
  // reduce across the 4 threads (same wave, consecutive lanes) owning row m
  esum += __shfl_down(esum, 2, 4);
  esum += __shfl_down(esum, 1, 4);
  if (q == 0) atomicAdd(&rs[m], esum);
}

// ---------------- final mix: out = exp(l)/rs * p_gen + copy*(1-p_gen) ----------------
__global__ void final_kernel(const short* __restrict__ logits_bf, const float* __restrict__ rs,
                             const float* __restrict__ pgen,
                             const float* __restrict__ copy, float* __restrict__ out) {
  int i = blockIdx.x * 256 + threadIdx.x;     // over 800000 groups of 4
  int b = (i * 4) / VV;
  float p = pgen[b], s = rs[b];
  short4v l = ((const short4v*)logits_bf)[i];
  float4 c = ((const float4*)copy)[i];
  float q = 1.f - p;
  float ps = p / s;
  float4 o;
  o.x = expf(bf2f(l[0])) * ps + c.x * q;
  o.y = expf(bf2f(l[1])) * ps + c.y * q;
  o.z = expf(bf2f(l[2])) * ps + c.z * q;
  o.w = expf(bf2f(l[3])) * ps + c.w * q;
  ((float4*)out)[i] = o;
}

extern "C" void kernel_launch(void* const* d_in, const int* in_sizes, int n_in,
                              void* d_out, int out_size, void* d_ws, size_t ws_size,
                              hipStream_t stream) {
  const int*   ids  = (const int*)d_in[0];
  const float* preh = (const float*)d_in[1];
  const float* enc  = (const float*)d_in[2];
  const int*   src  = (const int*)d_in[3];
  const float* cov  = (const float*)d_in[4];
  const float* embt = (const float*)d_in[5];
  const float* Wih0 = (const float*)d_in[6];
  const float* Whh0 = (const float*)d_in[7];
  const float* bih0 = (const float*)d_in[8];
  const float* bhh0 = (const float*)d_in[9];
  const float* Wih1 = (const float*)d_in[10];
  const float* Whh1 = (const float*)d_in[11];
  const float* bih1 = (const float*)d_in[12];
  const float* bhh1 = (const float*)d_in[13];
  const float* aW   = (const float*)d_in[14];
  const float* ab   = (const float*)d_in[15];
  const float* covW = (const float*)d_in[16];
  const float* covb = (const float*)d_in[17];
  const float* f1W  = (const float*)d_in[18];
  const float* f1b  = (const float*)d_in[19];
  const float* f2W  = (const float*)d_in[20];
  const float* f2b  = (const float*)d_in[21];
  const float* gW   = (const float*)d_in[22];
  const float* gb   = (const float*)d_in[23];
  float* out = (float*)d_out;
  float* ws  = (float*)d_ws;

  zero_prep_kernel<<<3125, 256, 0, stream>>>(out + OFF_COPY, out + OFF_LOSS, ws + WS_RS,
                                             embt, ids, preh,
                                             (short*)(ws + WS_AX0), (short*)(ws + WS_AH0),
                                             (short*)(ws + WS_AH1));
  gru_mfma_kernel<EE><<<128, 384, 0, stream>>>(
      (const short*)(ws + WS_AX0), (const short*)(ws + WS_AH0),
      Wih0, Whh0, bih0, bhh0, preh,
      out + OFF_CURHID, out + OFF_CURHID, (short*)(ws + WS_AX1), HH);
  gru_mfma_kernel<HH><<<128, 384, 0, stream>>>(
      (const short*)(ws + WS_AX1), (const short*)(ws + WS_AH1),
      Wih1, Whh1, bih1, bhh1, preh + BB * HH,
      ws + WS_S, out + OFF_CURHID + BB * HH, (short*)(ws + WS_A1), H4);
  scores_kernel<<<dim3(100, 64), 256, 0, stream>>>(enc, cov, aW, ab, covW, covb,
                                                   ws + WS_S, ws + WS_TS);
  attn_kernel<<<64, 512, 0, stream>>>(ws + WS_TS, cov, src, ws + WS_ATTN, out,
                                      out + OFF_COPY);
  ctx_part_kernel<<<dim3(64, NCH), 512, 0, stream>>>(enc, ws + WS_ATTN, ws + WS_CTXP);
  ctxred_pgen_kernel<<<64, 512, 0, stream>>>(ws + WS_CTXP, ws + WS_S, embt, ids, gW, gb,
                                             (short*)(ws + WS_A1), ws + WS_PGEN);
  fc1_kernel<<<64, 256, 0, stream>>>((const short*)(ws + WS_A1), f1W, f1b,
                                     (short*)(ws + WS_NIB));
  fc2_kernel<<<782, 256, 0, stream>>>((const short*)(ws + WS_NIB), f2W, f2b,
                                      (short*)(ws + WS_LOGITS), ws + WS_RS);
  final_kernel<<<3125, 256, 0, stream>>>((const short*)(ws + WS_LOGITS), ws + WS_RS,
                                         ws + WS_PGEN, out + OFF_COPY, out);
}